// Round 11
// baseline (4686.246 us; speedup 1.0000x reference)
//
#include <hip/hip_runtime.h>
#include <stdint.h>
#include <math.h>

// Problem dims
#define SEQL 70
#define BAT 80
#define EMBD 400
#define HIDD 1150
#define GATES 4600        // 4*HIDD
#define NTOKV 33278
#define MALL 5600         // SEQL*BAT
// Padded dims
#define KH 1152
#define KE 416
#define N4P 4608
#define NVP 33280
// persistent LSTM kernel
#define NBLK 72
// fragment-tiled layouts: chunk(rowblock rb, kchunk kc) = (rb*KC + kc)*512,
// within-chunk offset for (row b, col c): ((c>>3)&3)*128 + (b&15)*8 + (c&7)
// == lane*8 where lane = (c/8 within 32)*16 + b%16  -> lane*16B contiguous.
#define KC_H 36
#define HSLAB (80 * KH)       // 92160 el per t-slab (5 rowblocks x 36 x 512)
#define KC_E 13
#define XSLAB (80 * KE)       // 33280
#define WTBLK (4 * 36 * 512)  // lstm per-j-block W copy

typedef __bf16 bf16;
typedef bf16 bf16x8 __attribute__((ext_vector_type(8)));
typedef float f32x4 __attribute__((ext_vector_type(4)));

__device__ __forceinline__ float ld_in(const void* p, size_t i, int f32w) {
    return f32w ? ((const float*)p)[i] : (float)((const bf16*)p)[i];
}
__device__ __forceinline__ float clampdiag(float v) {
    return fminf(fmaxf(v, -30000.f), 30000.f);
}
__device__ __forceinline__ void store_h_sc1(bf16* addr, uint32_t bits) {
    asm volatile("global_store_short %0, %1, off sc0 sc1"
                 :: "v"(addr), "v"(bits) : "memory");
}
// async global->LDS, 16B/lane: LDS dest = uniform base + lane*16 (linear);
// global source per-lane = chunkBase + lane*16 (fragment-tiled layout).
__device__ __forceinline__ void gload_lds16(const bf16* g, bf16* l) {
    __builtin_amdgcn_global_load_lds(
        (const __attribute__((address_space(1))) void*)g,
        (__attribute__((address_space(3))) void*)l, 16, 0, 0);
}
__device__ __forceinline__ size_t tflat(int b, int c, int KC) {
    return (size_t)(b >> 4) * KC * 512 + (size_t)(c >> 5) * 512
         + (size_t)((c >> 3) & 3) * 128 + (size_t)(b & 15) * 8 + (c & 7);
}

// ---------------------------------------------------------------------------
__global__ void detect_dtype(const void* __restrict__ emb, int* __restrict__ flag)
{
    __shared__ int fails;
    if (threadIdx.x == 0) fails = 0;
    __syncthreads();
    const uint32_t* w = (const uint32_t*)emb;
    int f = 0;
    for (int i = threadIdx.x; i < 1024; i += blockDim.x) {
        uint32_t h0 = w[i] & 0xFFFFu;
        uint32_t e0 = (h0 >> 7) & 0xFFu;
        if (e0 > 122u) f++;
    }
    atomicAdd(&fails, f);
    __syncthreads();
    if (threadIdx.x == 0) *flag = (fails > 100) ? 1 : 0;
}

// ---------------------------------------------------------------------------
// GEMM v2: A tiled (KC,ASLAB; 80-row slabs), B tiled rowblock-major.
// global_load_lds(16B) staging into linear 1KB LDS chunks; conflict-free
// lane*16B ds_reads. C[m,n] = sum_k A[m,k]B[n,k] + bias[n].
// ---------------------------------------------------------------------------
__global__ __launch_bounds__(256)
void gemm_bt(const bf16* __restrict__ A, int KC, int ASLAB,
             const bf16* __restrict__ Bt,
             const float* __restrict__ bias,
             void* __restrict__ Cp, long long ldc,
             int M, int Nout, int outMode, const int* __restrict__ dflag,
             int gx, int gy)
{
    __shared__ __align__(16) bf16 As[8 * 512];
    __shared__ __align__(16) bf16 Bs[8 * 512];
    const int f32w = *dflag;
    const int tid  = threadIdx.x;
    const int lane = tid & 63;
    const int w    = tid >> 6;

    const int Wb = 32;
    int id = blockIdx.x;
    int fullb = gx / Wb, tw = gx - fullb * Wb;
    int bx, by;
    if (id < fullb * Wb * gy) {
        int band = id / (Wb * gy), wi = id % (Wb * gy);
        bx = band * Wb + wi % Wb;
        by = wi / Wb;
    } else {
        int wi = id - fullb * Wb * gy;
        bx = fullb * Wb + wi % tw;
        by = wi / tw;
    }
    const int bm = by * 128;
    const int bn = bx * 128;

    // per-wave staging chunks (2 A + 2 B)
    const int c0 = 2 * w, c1 = 2 * w + 1;
    const int maxrb = M / 16 - 1;
    const int rA0 = min(by * 8 + c0, maxrb);
    const int rA1 = min(by * 8 + c1, maxrb);
    const bf16* gA0 = A + (size_t)(rA0 / 5) * ASLAB + (size_t)(rA0 % 5) * KC * 512 + (size_t)lane * 8;
    const bf16* gA1 = A + (size_t)(rA1 / 5) * ASLAB + (size_t)(rA1 % 5) * KC * 512 + (size_t)lane * 8;
    const bf16* gB0 = Bt + (size_t)(bn / 16 + c0) * KC * 512 + (size_t)lane * 8;
    const bf16* gB1 = Bt + (size_t)(bn / 16 + c1) * KC * 512 + (size_t)lane * 8;
    bf16* lA0 = &As[c0 * 512];
    bf16* lA1 = &As[c1 * 512];
    bf16* lB0 = &Bs[c0 * 512];
    bf16* lB1 = &Bs[c1 * 512];

    const int ra = (w >> 1) * 4;   // A rowblock group for this wave
    const int rb = (w & 1) * 4;    // B rowblock group

    f32x4 acc[4][4] = {};

    for (int kc = 0; kc < KC; ++kc) {
        __syncthreads();              // prev iter ds_reads complete
        gload_lds16(gA0 + (size_t)kc * 512, lA0);
        gload_lds16(gA1 + (size_t)kc * 512, lA1);
        gload_lds16(gB0 + (size_t)kc * 512, lB0);
        gload_lds16(gB1 + (size_t)kc * 512, lB1);
        asm volatile("s_waitcnt vmcnt(0)" ::: "memory");
        __syncthreads();
        bf16x8 af[4], bfv[4];
#pragma unroll
        for (int mi = 0; mi < 4; ++mi)
            af[mi] = *(const bf16x8*)&As[(ra + mi) * 512 + lane * 8];
#pragma unroll
        for (int ni = 0; ni < 4; ++ni)
            bfv[ni] = *(const bf16x8*)&Bs[(rb + ni) * 512 + lane * 8];
#pragma unroll
        for (int mi = 0; mi < 4; ++mi)
#pragma unroll
            for (int ni = 0; ni < 4; ++ni)
                acc[mi][ni] = __builtin_amdgcn_mfma_f32_16x16x32_bf16(
                    af[mi], bfv[ni], acc[mi][ni], 0, 0, 0);
    }

    const int wm = (w >> 1) * 64;
    const int wn = (w & 1) * 64;
    const int lr = lane & 15;
#pragma unroll
    for (int mi = 0; mi < 4; ++mi)
#pragma unroll
        for (int ni = 0; ni < 4; ++ni) {
            int n = bn + wn + ni * 16 + lr;
            if (n >= Nout) continue;
            float bv = bias[n];
#pragma unroll
            for (int rr = 0; rr < 4; ++rr) {
                int mm = bm + wm + mi * 16 + (lane >> 4) * 4 + rr;
                if (mm < M) {
                    float v = clampdiag(acc[mi][ni][rr] + bv);
                    size_t idx = (size_t)mm * ldc + n;
                    if (outMode == 0)      ((float*)Cp)[idx] = v;
                    else if (outMode == 1) ((bf16*)Cp)[idx] = (bf16)v;
                    else {
                        if (f32w) ((float*)Cp)[idx] = v;
                        else      ((bf16*)Cp)[idx] = (bf16)v;
                    }
                }
            }
        }
}

// ---------------------------------------------------------------------------
__device__ __forceinline__ void gridbar(int* ctr, int target)
{
    __syncthreads();
    if (threadIdx.x == 0) {
        atomicAdd(ctr, 1);
        int v;
        do {
            asm volatile("global_load_dword %0, %1, off sc0 sc1\n\t"
                         "s_waitcnt vmcnt(0)"
                         : "=v"(v) : "v"(ctr) : "memory");
        } while (v < target);
    }
    __syncthreads();
    asm volatile("" ::: "memory");
}

// ---------------------------------------------------------------------------
// Persistent per-layer LSTM v5.1: tiled contiguous loads, early G prefetch.
// VAR 0 = baseline; VAR 1 = +dup(45 H-loads + 180 MFMA); VAR 2 = +dup(180
// MFMA on resident regs). Marginals isolate load vs MFMA cost.
// ---------------------------------------------------------------------------
template<int VAR, typename GT>
__global__ __launch_bounds__(256, 1)
void lstm_layer(const bf16* __restrict__ WT,   // [72][4][36][512]
                const GT* __restrict__ G,      // [70][80][N4P]
                const bf16* __restrict__ H0,   // tiled slab
                float* __restrict__ Cst,       // [80][KH] row-major
                bf16* __restrict__ HA,         // [70] tiled slabs
                int* __restrict__ ctr)
{
    __shared__ __align__(16) float pl4[4][4][5][64][4];   // 80 KB
    const int tid  = threadIdx.x;
    const int lane = tid & 63;
    const int w    = tid >> 6;          // K-slice 0..3
    const int q    = lane >> 4;
    const int lr   = lane & 15;
    const int n0   = blockIdx.x * 16;
    const int jc   = n0 + lr;
    const bool jok = (jc < HIDD);

    const bf16* wtb = WT + (size_t)blockIdx.x * WTBLK + (size_t)(w * 9) * 512
                        + (size_t)lane * 8;
    const int kst = (n0 >> 5) * 512;
    const int qtp = ((n0 & 31) + lr) >> 3;
    const int eo  = lr & 7;

    const int QA = w;
    const bool hasB = (w == 0);
    const int QB = 4;

    float cregA[4], cregB[4];
#pragma unroll
    for (int rr = 0; rr < 4; ++rr) {
        cregA[rr] = jok ? Cst[(size_t)(QA * 16 + q * 4 + rr) * KH + jc] : 0.f;
        cregB[rr] = (hasB && jok) ? Cst[(size_t)(QB * 16 + q * 4 + rr) * KH + jc] : 0.f;
    }

    float gpA[16], gpB[16], gnA[16], gnB[16];
#pragma unroll
    for (int s = 0; s < 4; ++s)
#pragma unroll
        for (int rr = 0; rr < 4; ++rr) {
            gpA[s * 4 + rr] = jok ? (float)G[(size_t)(QA * 16 + q * 4 + rr) * N4P + s * HIDD + jc] : 0.f;
            gpB[s * 4 + rr] = (hasB && jok) ? (float)G[(size_t)(QB * 16 + q * 4 + rr) * N4P + s * HIDD + jc] : 0.f;
        }

    for (int t = 0; t < SEQL; ++t) {
        const bf16* Hin = t ? (HA + (size_t)(t - 1) * HSLAB) : H0;
        bf16*       HAt = HA + (size_t)t * HSLAB;
        const bf16* hb  = Hin + (size_t)(w * 9) * 512 + (size_t)lane * 8;

        // ---- burst loads: 36 W + 45 H fragments, contiguous 1KB each ----
        bf16x8 bfr[4][9], a[5][9];
#pragma unroll
        for (int s = 0; s < 4; ++s)
#pragma unroll
            for (int k = 0; k < 9; ++k)
                bfr[s][k] = *(const bf16x8*)(wtb + (size_t)(s * 36 + k) * 512);
#pragma unroll
        for (int mi = 0; mi < 5; ++mi)
#pragma unroll
            for (int k = 0; k < 9; ++k)
                a[mi][k] = *(const bf16x8*)(hb + (size_t)(mi * 36 + k) * 512);

        // ---- early G(t+1) prefetch: drains under MFMA + epilogue ----
        if (t + 1 < SEQL) {
            const GT* g1 = G + (size_t)(t + 1) * BAT * N4P;
#pragma unroll
            for (int s = 0; s < 4; ++s)
#pragma unroll
                for (int rr = 0; rr < 4; ++rr) {
                    gnA[s * 4 + rr] = jok ? (float)g1[(size_t)(QA * 16 + q * 4 + rr) * N4P + s * HIDD + jc] : 0.f;
                    gnB[s * 4 + rr] = (hasB && jok) ? (float)g1[(size_t)(QB * 16 + q * 4 + rr) * N4P + s * HIDD + jc] : 0.f;
                }
        }

        // ---- 180 MFMAs ----
        f32x4 acc[4][5] = {};
#pragma unroll
        for (int mi = 0; mi < 5; ++mi)
#pragma unroll
            for (int k = 0; k < 9; ++k)
#pragma unroll
                for (int s = 0; s < 4; ++s)
                    acc[s][mi] = __builtin_amdgcn_mfma_f32_16x16x32_bf16(
                        a[mi][k], bfr[s][k], acc[s][mi], 0, 0, 0);

        if constexpr (VAR == 1) {   // dup loads + MFMA
            const bf16* hb2 = hb;
            asm volatile("" : "+v"(hb2));
            f32x4 accD[4][5] = {};
#pragma unroll
            for (int mi = 0; mi < 5; ++mi)
#pragma unroll
                for (int k = 0; k < 9; ++k) {
                    bf16x8 av = *(const bf16x8*)(hb2 + (size_t)(mi * 36 + k) * 512);
#pragma unroll
                    for (int s = 0; s < 4; ++s)
                        accD[s][mi] = __builtin_amdgcn_mfma_f32_16x16x32_bf16(
                            av, bfr[s][k], accD[s][mi], 0, 0, 0);
                }
#pragma unroll
            for (int s = 0; s < 4; ++s)
#pragma unroll
                for (int mi = 0; mi < 5; ++mi)
                    asm volatile("" :: "v"(accD[s][mi][0]), "v"(accD[s][mi][1]),
                                       "v"(accD[s][mi][2]), "v"(accD[s][mi][3]));
        }
        if constexpr (VAR == 2) {   // dup MFMA only (resident operands)
            f32x4 accD[4][5] = {};
#pragma unroll
            for (int mi = 0; mi < 5; ++mi)
#pragma unroll
                for (int k = 0; k < 9; ++k)
#pragma unroll
                    for (int s = 0; s < 4; ++s)
                        accD[s][mi] = __builtin_amdgcn_mfma_f32_16x16x32_bf16(
                            a[mi][k], bfr[s][k], accD[s][mi], 0, 0, 0);
#pragma unroll
            for (int s = 0; s < 4; ++s)
#pragma unroll
                for (int mi = 0; mi < 5; ++mi)
                    asm volatile("" :: "v"(accD[s][mi][0]), "v"(accD[s][mi][1]),
                                       "v"(accD[s][mi][2]), "v"(accD[s][mi][3]));
        }

        // ---- cross-wave K-reduction ----
#pragma unroll
        for (int s = 0; s < 4; ++s)
#pragma unroll
            for (int mi = 0; mi < 5; ++mi)
                *(f32x4*)&pl4[w][s][mi][lane][0] = acc[s][mi];
        __syncthreads();

        // ---- consume QA (all waves) + QB (wave 0) ----
        {
            f32x4 p[4];
#pragma unroll
            for (int s = 0; s < 4; ++s)
                p[s] = *(const f32x4*)&pl4[0][s][QA][lane][0]
                     + *(const f32x4*)&pl4[1][s][QA][lane][0]
                     + *(const f32x4*)&pl4[2][s][QA][lane][0]
                     + *(const f32x4*)&pl4[3][s][QA][lane][0];
            if (jok) {
#pragma unroll
                for (int rr = 0; rr < 4; ++rr) {
                    float pi = p[0][rr] + gpA[0 + rr];
                    float pf = p[1][rr] + gpA[4 + rr];
                    float po = p[2][rr] + gpA[8 + rr];
                    float pg = p[3][rr] + gpA[12 + rr];
                    float ii = 1.f / (1.f + expf(-pi));
                    float ff = 1.f / (1.f + expf(-pf));
                    float oo = 1.f / (1.f + expf(-po));
                    float gg = tanhf(pg);
                    float cn = ff * cregA[rr] + ii * gg;
                    cregA[rr] = cn;
                    bf16 hv = (bf16)(oo * tanhf(cn));
                    store_h_sc1(HAt + (size_t)QA * 18432 + kst + qtp * 128 + (q * 4 + rr) * 8 + eo,
                                (uint32_t)__builtin_bit_cast(unsigned short, hv));
                }
            }
        }
        if (hasB) {
            f32x4 p[4];
#pragma unroll
            for (int s = 0; s < 4; ++s)
                p[s] = *(const f32x4*)&pl4[0][s][QB][lane][0]
                     + *(const f32x4*)&pl4[1][s][QB][lane][0]
                     + *(const f32x4*)&pl4[2][s][QB][lane][0]
                     + *(const f32x4*)&pl4[3][s][QB][lane][0];
            if (jok) {
#pragma unroll
                for (int rr = 0; rr < 4; ++rr) {
                    float pi = p[0][rr] + gpB[0 + rr];
                    float pf = p[1][rr] + gpB[4 + rr];
                    float po = p[2][rr] + gpB[8 + rr];
                    float pg = p[3][rr] + gpB[12 + rr];
                    float ii = 1.f / (1.f + expf(-pi));
                    float ff = 1.f / (1.f + expf(-pf));
                    float oo = 1.f / (1.f + expf(-po));
                    float gg = tanhf(pg);
                    float cn = ff * cregB[rr] + ii * gg;
                    cregB[rr] = cn;
                    bf16 hv = (bf16)(oo * tanhf(cn));
                    store_h_sc1(HAt + (size_t)QB * 18432 + kst + qtp * 128 + (q * 4 + rr) * 8 + eo,
                                (uint32_t)__builtin_bit_cast(unsigned short, hv));
                }
            }
        }

        if (t < SEQL - 1) {
            asm volatile("s_waitcnt vmcnt(0)" ::: "memory");  // H stores + G at L3
            gridbar(ctr, NBLK * (t + 1));
#pragma unroll
            for (int i = 0; i < 16; ++i) { gpA[i] = gnA[i]; gpB[i] = gnB[i]; }
        }
    }

    if (jok) {
#pragma unroll
        for (int rr = 0; rr < 4; ++rr)
            Cst[(size_t)(QA * 16 + q * 4 + rr) * KH + jc] = cregA[rr];
        if (hasB) {
#pragma unroll
            for (int rr = 0; rr < 4; ++rr)
                Cst[(size_t)(QB * 16 + q * 4 + rr) * KH + jc] = cregB[rr];
        }
    }
}

__global__ void bar_reset(int* ctr) { if (threadIdx.x == 0) *ctr = 0; }

// ---------------------------------------------------------------------------
// Prep kernels
// ---------------------------------------------------------------------------
// generic B-matrix -> rowblock-major fragment tiles [NB][KC][512]
__global__ void pad_wtB(const void* __restrict__ src, bf16* __restrict__ dst,
                        int N, int K, int NB, int KC, const int* __restrict__ dflag)
{
    const int f32w = *dflag;
    size_t total = (size_t)NB * KC * 512;
    for (size_t i = (size_t)blockIdx.x * blockDim.x + threadIdx.x; i < total;
         i += (size_t)gridDim.x * blockDim.x) {
        int o  = (int)(i & 511);
        size_t ci = i >> 9;
        int kc = (int)(ci % KC);
        int nb = (int)(ci / KC);
        int kq = o >> 7, r16 = (o >> 3) & 15, e = o & 7;
        int n = nb * 16 + r16;
        int c = kc * 32 + kq * 8 + e;
        dst[i] = (n < N && c < K) ? (bf16)ld_in(src, (size_t)n * K + c, f32w)
                                  : (bf16)0.f;
    }
}

// Whh -> lstm per-block fragment-tiled WT [72][4][36][512]
__global__ void pad_wt(const void* __restrict__ src, bf16* __restrict__ dst,
                       const int* __restrict__ dflag)
{
    const int f32w = *dflag;
    const size_t total = (size_t)NBLK * WTBLK;
    for (size_t i = (size_t)blockIdx.x * blockDim.x + threadIdx.x; i < total;
         i += (size_t)gridDim.x * blockDim.x) {
        int e  = (int)(i & 7);
        int ln = (int)((i >> 3) & 63);
        size_t tile = i >> 9;
        int kg = (int)(tile % 36);
        size_t sb = tile / 36;
        int s   = (int)(sb & 3);
        int blk = (int)(sb >> 2);
        int jr  = blk * 16 + (ln & 15);
        int col = kg * 32 + (ln >> 4) * 8 + e;
        bf16 v = (bf16)0.f;
        if (jr < HIDD && col < HIDD)
            v = (bf16)ld_in(src, (size_t)(s * HIDD + jr) * HIDD + col, f32w);
        dst[i] = v;
    }
}

__global__ void combine_bias(const void* a, const void* b, float* o, int n, int np,
                             const int* __restrict__ dflag)
{
    const int f32w = *dflag;
    int i = blockIdx.x * blockDim.x + threadIdx.x;
    if (i < np) o[i] = (i < n) ? ld_in(a, i, f32w) + ld_in(b, i, f32w) : 0.f;
}

__global__ void cvt_bias(const void* a, float* o, int n, int np,
                         const int* __restrict__ dflag)
{
    const int f32w = *dflag;
    int i = blockIdx.x * blockDim.x + threadIdx.x;
    if (i < np) o[i] = (i < n) ? ld_in(a, i, f32w) : 0.f;
}

__global__ void embed_gather(const int* __restrict__ x, const void* __restrict__ emb,
                             bf16* __restrict__ XE, const int* __restrict__ dflag)
{
    const int f32w = *dflag;
    int row = blockIdx.x;                       // t*80+b
    int xi  = x[row];
    int b   = row % 80;
    bf16* base = XE + (size_t)(row / 80) * XSLAB;
    for (int c = threadIdx.x; c < KE; c += blockDim.x) {
        float v = (c < EMBD) ? ld_in(emb, (size_t)xi * EMBD + c, f32w) : 0.f;
        base[tflat(b, c, KC_E)] = (bf16)v;
    }
}

__global__ void zero_ha_pad(bf16* HA)
{
    int i = blockIdx.x * blockDim.x + threadIdx.x;
    if (i < MALL * 2) {
        int r = i >> 1;
        int t = r / BAT, b = r - t * BAT;
        int j = HIDD + (i & 1);
        HA[(size_t)t * HSLAB + tflat(b, j, KC_H)] = (bf16)0.f;
    }
}

__global__ void init_state(const void* __restrict__ h0, const void* __restrict__ c0,
                           size_t lofs, bf16* H0buf, float* Cst,
                           const int* __restrict__ dflag)
{
    const int f32w = *dflag;
    int i = blockIdx.x * blockDim.x + threadIdx.x;
    if (i >= BAT * KH) return;
    int b = i / KH, j = i % KH;
    float hv = 0.f, cv = 0.f;
    if (j < HIDD) {
        hv = ld_in(h0, lofs + (size_t)b * HIDD + j, f32w);
        cv = ld_in(c0, lofs + (size_t)b * HIDD + j, f32w);
    }
    H0buf[tflat(b, j, KC_H)] = (bf16)hv;
    Cst[i] = cv;
}

__global__ void write_tail(const bf16* __restrict__ Hfin, const float* __restrict__ Cfin,
                           void* __restrict__ outBase, size_t hOfs, size_t cOfs,
                           const int* __restrict__ dflag)
{
    const int f32w = *dflag;
    int i = blockIdx.x * blockDim.x + threadIdx.x;
    if (i >= BAT * HIDD) return;
    int b = i / HIDD, j = i % HIDD;
    float hv = clampdiag((float)Hfin[tflat(b, j, KC_H)]);
    float cv = clampdiag(Cfin[b * KH + j]);
    if (f32w) {
        ((float*)outBase)[hOfs + i] = hv;
        ((float*)outBase)[cOfs + i] = cv;
    } else {
        ((bf16*)outBase)[hOfs + i] = (bf16)hv;
        ((bf16*)outBase)[cOfs + i] = (bf16)cv;
    }
}

__global__ void sentinel_kernel(void* out, float v, const int* __restrict__ dflag)
{
    if (blockIdx.x == 0 && threadIdx.x == 0) {
        if (*dflag) ((float*)out)[0] = v;
        else        ((bf16*)out)[0] = (bf16)v;
    }
}

// ---------------------------------------------------------------------------
extern "C" void kernel_launch(void* const* d_in, const int* in_sizes, int n_in,
                              void* d_out, int out_size, void* d_ws, size_t ws_size,
                              hipStream_t stream)
{
    const int*  x    = (const int*)d_in[0];
    const void* h0   = d_in[1];
    const void* c0   = d_in[2];
    const void* emb  = d_in[3];
    const void* wih[3] = {d_in[4], d_in[8],  d_in[12]};
    const void* bih[3] = {d_in[5], d_in[9],  d_in[13]};
    const void* whh[3] = {d_in[6], d_in[10], d_in[14]};
    const void* bhh[3] = {d_in[7], d_in[11], d_in[15]};
    const void* wdec = d_in[16];
    const void* bdec = d_in[17];
    const size_t DEC = (size_t)MALL * NTOKV;
    (void)in_sizes; (void)n_in; (void)out_size;

    auto al = [](size_t v) { return (v + 255) & ~(size_t)255; };
    const size_t wdecB = al((size_t)NVP * KH * 2);
    auto plan = [&](bool gbf, size_t* offs) -> size_t {
        size_t off = 0;
        auto carve = [&](size_t b) { size_t p = off; off += al(b); return p; };
        offs[0] = carve((size_t)MALL * N4P * (gbf ? 2 : 4));     // G
        offs[1] = carve((size_t)MALL * KE * 2);                  // XE tiled
        offs[2] = carve((size_t)N4P * KH * 2);                   // WihP tiled
        offs[3] = carve((size_t)NBLK * WTBLK * 2);               // WT
        if (off < wdecB) off = wdecB;
        offs[4] = carve((size_t)MALL * KH * 2);                  // HA tiled
        offs[5] = carve((size_t)N4P * 4);                        // bc
        offs[6] = carve((size_t)NVP * 4);                        // bd
        offs[7] = carve((size_t)BAT * KH * 2);                   // H0 tiled
        offs[8] = carve((size_t)BAT * KH * 4);                   // Cst
        offs[9] = carve(256);                                    // dflag + barrier
        return off;
    };
    size_t offs[10];
    size_t needA = plan(false, offs);
    size_t needB = plan(true, offs);
    bool gbf16;
    if (ws_size >= needA)      { gbf16 = false; plan(false, offs); }
    else if (ws_size >= needB) { gbf16 = true;  plan(true,  offs); }
    else {
        int* dflag = (int*)d_ws;
        detect_dtype<<<1, 256, 0, stream>>>(emb, dflag);
        float mb = (float)(ws_size >> 20);
        if (mb > 20000.f) mb = 20000.f;
        sentinel_kernel<<<1, 64, 0, stream>>>(d_out, 700.f + mb, dflag);
        return;
    }

    char* ws = (char*)d_ws;
    void* G      = ws + offs[0];
    bf16* XE     = (bf16*)(ws + offs[1]);
    bf16* WihP   = (bf16*)(ws + offs[2]);
    bf16* WT     = (bf16*)(ws + offs[3]);
    bf16* WdecP  = (bf16*)(ws + 0);
    bf16* HA     = (bf16*)(ws + offs[4]);
    float* bc    = (float*)(ws + offs[5]);
    float* bd    = (float*)(ws + offs[6]);
    bf16* H0buf  = (bf16*)(ws + offs[7]);
    float* Cst   = (float*)(ws + offs[8]);
    int*  dflag  = (int*)(ws + offs[9]);
    int*  barctr = (int*)(ws + offs[9] + 128);

    detect_dtype<<<1, 256, 0, stream>>>(emb, dflag);
    embed_gather<<<MALL, 128, 0, stream>>>(x, emb, XE, dflag);
    zero_ha_pad<<<(MALL * 2 + 255) / 256, 256, 0, stream>>>(HA);

    for (int l = 0; l < 3; ++l) {
        int Kin = (l == 0) ? EMBD : HIDD;
        int kc  = (l == 0) ? KC_E : KC_H;
        int asl = (l == 0) ? XSLAB : HSLAB;
        pad_wtB<<<2048, 256, 0, stream>>>(wih[l], WihP, GATES, Kin, N4P / 16, kc, dflag);
        pad_wt<<<2048, 256, 0, stream>>>(whh[l], WT, dflag);
        combine_bias<<<(N4P + 255) / 256, 256, 0, stream>>>(bih[l], bhh[l], bc, GATES, N4P, dflag);
        init_state<<<(BAT * KH + 255) / 256, 256, 0, stream>>>(
            h0, c0, (size_t)l * BAT * HIDD, H0buf, Cst, dflag);
        bar_reset<<<1, 64, 0, stream>>>(barctr);
        const bf16* Ain = (l == 0) ? XE : HA;
        {
            int gx = N4P / 128, gy = (MALL + 127) / 128;
            gemm_bt<<<gx * gy, 256, 0, stream>>>(
                Ain, kc, asl, WihP, bc, G, N4P, MALL, N4P,
                gbf16 ? 1 : 0, dflag, gx, gy);
        }
        if (gbf16) {
            if (l == 0)      lstm_layer<0, bf16><<<NBLK, 256, 0, stream>>>(WT, (const bf16*)G, H0buf, Cst, HA, barctr);
            else if (l == 1) lstm_layer<1, bf16><<<NBLK, 256, 0, stream>>>(WT, (const bf16*)G, H0buf, Cst, HA, barctr);
            else             lstm_layer<2, bf16><<<NBLK, 256, 0, stream>>>(WT, (const bf16*)G, H0buf, Cst, HA, barctr);
        } else {
            if (l == 0)      lstm_layer<0, float><<<NBLK, 256, 0, stream>>>(WT, (const float*)G, H0buf, Cst, HA, barctr);
            else if (l == 1) lstm_layer<1, float><<<NBLK, 256, 0, stream>>>(WT, (const float*)G, H0buf, Cst, HA, barctr);
            else             lstm_layer<2, float><<<NBLK, 256, 0, stream>>>(WT, (const float*)G, H0buf, Cst, HA, barctr);
        }
        write_tail<<<(BAT * HIDD + 255) / 256, 256, 0, stream>>>(
            HA + (size_t)(SEQL - 1) * HSLAB, Cst, d_out,
            DEC + (size_t)l * BAT * HIDD,
            DEC + (size_t)3 * BAT * HIDD + (size_t)l * BAT * HIDD, dflag);
    }

    pad_wtB<<<4096, 256, 0, stream>>>(wdec, WdecP, NTOKV, HIDD, NVP / 16, KC_H, dflag);
    cvt_bias<<<(NVP + 255) / 256, 256, 0, stream>>>(bdec, bd, NTOKV, NVP, dflag);
    {
        int gx = NVP / 128, gy = (MALL + 127) / 128;
        gemm_bt<<<gx * gy, 256, 0, stream>>>(
            HA, KC_H, HSLAB, WdecP, bd, d_out, NTOKV, MALL, NTOKV, 2, dflag, gx, gy);
    }
}

// Round 12
// 2997.199 us; speedup vs baseline: 1.5635x; 1.5635x over previous
//
#include <hip/hip_runtime.h>
#include <stdint.h>
#include <math.h>

// Problem dims
#define SEQL 70
#define BAT 80
#define EMBD 400
#define HIDD 1150
#define GATES 4600        // 4*HIDD
#define NTOKV 33278
#define MALL 5600         // SEQL*BAT
// Padded dims
#define KH 1152
#define KE 416
#define N4P 4608
#define NVP 33280
// persistent LSTM kernel
#define NBLK 72
// fragment-tiled layouts: chunk(rowblock rb, kchunk kc) = (rb*KC + kc)*512,
// within-chunk offset for (row b, col c): ((c>>3)&3)*128 + (b&15)*8 + (c&7)
#define KC_H 36
#define HSLAB (80 * KH)       // 92160 el per t-slab (5 rowblocks x 36 x 512)
#define KC_E 13
#define XSLAB (80 * KE)       // 33280
#define WTBLK (4 * 36 * 512)  // lstm per-j-block W copy

typedef __bf16 bf16;
typedef bf16 bf16x8 __attribute__((ext_vector_type(8)));
typedef float f32x4 __attribute__((ext_vector_type(4)));

__device__ __forceinline__ float ld_in(const void* p, size_t i, int f32w) {
    return f32w ? ((const float*)p)[i] : (float)((const bf16*)p)[i];
}
__device__ __forceinline__ float clampdiag(float v) {
    return fminf(fmaxf(v, -30000.f), 30000.f);
}
__device__ __forceinline__ void store_h_sc1(bf16* addr, uint32_t bits) {
    asm volatile("global_store_short %0, %1, off sc0 sc1"
                 :: "v"(addr), "v"(bits) : "memory");
}
// async global->LDS: dest = wave-uniform base + lane*width; global src per-lane.
__device__ __forceinline__ void gload_lds16(const bf16* g, bf16* l) {
    __builtin_amdgcn_global_load_lds(
        (const __attribute__((address_space(1))) void*)g,
        (__attribute__((address_space(3))) void*)l, 16, 0, 0);
}
__device__ __forceinline__ void gload_lds4(const float* g, float* l) {
    __builtin_amdgcn_global_load_lds(
        (const __attribute__((address_space(1))) void*)g,
        (__attribute__((address_space(3))) void*)l, 4, 0, 0);
}
__device__ __forceinline__ size_t tflat(int b, int c, int KC) {
    return (size_t)(b >> 4) * KC * 512 + (size_t)(c >> 5) * 512
         + (size_t)((c >> 3) & 3) * 128 + (size_t)(b & 15) * 8 + (c & 7);
}
// fast gates: |err| ~1e-6 relative, safe at extremes
__device__ __forceinline__ float fsig(float x) { return 1.f / (1.f + __expf(-x)); }
__device__ __forceinline__ float ftanh(float x) {
    float e = __expf(-2.f * fabsf(x));
    float r = (1.f - e) / (1.f + e);
    return copysignf(r, x);
}

// ---------------------------------------------------------------------------
__global__ void detect_dtype(const void* __restrict__ emb, int* __restrict__ flag)
{
    __shared__ int fails;
    if (threadIdx.x == 0) fails = 0;
    __syncthreads();
    const uint32_t* w = (const uint32_t*)emb;
    int f = 0;
    for (int i = threadIdx.x; i < 1024; i += blockDim.x) {
        uint32_t h0 = w[i] & 0xFFFFu;
        uint32_t e0 = (h0 >> 7) & 0xFFu;
        if (e0 > 122u) f++;
    }
    atomicAdd(&fails, f);
    __syncthreads();
    if (threadIdx.x == 0) *flag = (fails > 100) ? 1 : 0;
}

// ---------------------------------------------------------------------------
// GEMM v2 (validated r11): tiled A/B, global_load_lds staging, conflict-free.
// ---------------------------------------------------------------------------
__global__ __launch_bounds__(256)
void gemm_bt(const bf16* __restrict__ A, int KC, int ASLAB,
             const bf16* __restrict__ Bt,
             const float* __restrict__ bias,
             void* __restrict__ Cp, long long ldc,
             int M, int Nout, int outMode, const int* __restrict__ dflag,
             int gx, int gy)
{
    __shared__ __align__(16) bf16 As[8 * 512];
    __shared__ __align__(16) bf16 Bs[8 * 512];
    const int f32w = *dflag;
    const int tid  = threadIdx.x;
    const int lane = tid & 63;
    const int w    = tid >> 6;

    const int Wb = 32;
    int id = blockIdx.x;
    int fullb = gx / Wb, tw = gx - fullb * Wb;
    int bx, by;
    if (id < fullb * Wb * gy) {
        int band = id / (Wb * gy), wi = id % (Wb * gy);
        bx = band * Wb + wi % Wb;
        by = wi / Wb;
    } else {
        int wi = id - fullb * Wb * gy;
        bx = fullb * Wb + wi % tw;
        by = wi / tw;
    }
    const int bm = by * 128;
    const int bn = bx * 128;

    const int c0 = 2 * w, c1 = 2 * w + 1;
    const int maxrb = M / 16 - 1;
    const int rA0 = min(by * 8 + c0, maxrb);
    const int rA1 = min(by * 8 + c1, maxrb);
    const bf16* gA0 = A + (size_t)(rA0 / 5) * ASLAB + (size_t)(rA0 % 5) * KC * 512 + (size_t)lane * 8;
    const bf16* gA1 = A + (size_t)(rA1 / 5) * ASLAB + (size_t)(rA1 % 5) * KC * 512 + (size_t)lane * 8;
    const bf16* gB0 = Bt + (size_t)(bn / 16 + c0) * KC * 512 + (size_t)lane * 8;
    const bf16* gB1 = Bt + (size_t)(bn / 16 + c1) * KC * 512 + (size_t)lane * 8;
    bf16* lA0 = &As[c0 * 512];
    bf16* lA1 = &As[c1 * 512];
    bf16* lB0 = &Bs[c0 * 512];
    bf16* lB1 = &Bs[c1 * 512];

    const int ra = (w >> 1) * 4;
    const int rb = (w & 1) * 4;

    f32x4 acc[4][4] = {};

    for (int kc = 0; kc < KC; ++kc) {
        __syncthreads();
        gload_lds16(gA0 + (size_t)kc * 512, lA0);
        gload_lds16(gA1 + (size_t)kc * 512, lA1);
        gload_lds16(gB0 + (size_t)kc * 512, lB0);
        gload_lds16(gB1 + (size_t)kc * 512, lB1);
        asm volatile("s_waitcnt vmcnt(0)" ::: "memory");
        __syncthreads();
        bf16x8 af[4], bfv[4];
#pragma unroll
        for (int mi = 0; mi < 4; ++mi)
            af[mi] = *(const bf16x8*)&As[(ra + mi) * 512 + lane * 8];
#pragma unroll
        for (int ni = 0; ni < 4; ++ni)
            bfv[ni] = *(const bf16x8*)&Bs[(rb + ni) * 512 + lane * 8];
#pragma unroll
        for (int mi = 0; mi < 4; ++mi)
#pragma unroll
            for (int ni = 0; ni < 4; ++ni)
                acc[mi][ni] = __builtin_amdgcn_mfma_f32_16x16x32_bf16(
                    af[mi], bfv[ni], acc[mi][ni], 0, 0, 0);
    }

    const int wm = (w >> 1) * 64;
    const int wn = (w & 1) * 64;
    const int lr = lane & 15;
#pragma unroll
    for (int mi = 0; mi < 4; ++mi)
#pragma unroll
        for (int ni = 0; ni < 4; ++ni) {
            int n = bn + wn + ni * 16 + lr;
            if (n >= Nout) continue;
            float bv = bias[n];
#pragma unroll
            for (int rr = 0; rr < 4; ++rr) {
                int mm = bm + wm + mi * 16 + (lane >> 4) * 4 + rr;
                if (mm < M) {
                    float v = clampdiag(acc[mi][ni][rr] + bv);
                    size_t idx = (size_t)mm * ldc + n;
                    if (outMode == 0)      ((float*)Cp)[idx] = v;
                    else if (outMode == 1) ((bf16*)Cp)[idx] = (bf16)v;
                    else {
                        if (f32w) ((float*)Cp)[idx] = v;
                        else      ((bf16*)Cp)[idx] = (bf16)v;
                    }
                }
            }
        }
}

// ---------------------------------------------------------------------------
__device__ __forceinline__ void gridbar(int* ctr, int target)
{
    __syncthreads();
    if (threadIdx.x == 0) {
        atomicAdd(ctr, 1);
        int v;
        do {
            asm volatile("global_load_dword %0, %1, off sc0 sc1\n\t"
                         "s_waitcnt vmcnt(0)"
                         : "=v"(v) : "v"(ctr) : "memory");
        } while (v < target);
    }
    __syncthreads();
    asm volatile("" ::: "memory");
}

// ---------------------------------------------------------------------------
// Persistent per-layer LSTM v6: r10 structure + G via async LDS (zero VGPR)
// + fast gates. Single variant (r11's VAR templates caused 256-VGPR spills).
// ---------------------------------------------------------------------------
template<typename GT>
__global__ __launch_bounds__(256, 1)
void lstm_layer(const bf16* __restrict__ WT,   // [72][4][36][512]
                const GT* __restrict__ G,      // [70][80][N4P]
                const bf16* __restrict__ H0,   // tiled slab
                float* __restrict__ Cst,       // [80][KH] row-major
                bf16* __restrict__ HA,         // [70] tiled slabs
                int* __restrict__ ctr)
{
    constexpr bool GF32 = (sizeof(GT) == 4);
    __shared__ __align__(16) float pl4[4][4][5][64][4];   // 80 KB
    __shared__ __align__(16) float gl[5][16][64];         // 20 KB
    const int tid  = threadIdx.x;
    const int lane = tid & 63;
    const int w    = tid >> 6;          // K-slice 0..3
    const int q    = lane >> 4;
    const int lr   = lane & 15;
    const int n0   = blockIdx.x * 16;
    const int jc   = n0 + lr;
    const bool jok = (jc < HIDD);

    const bf16* wtb = WT + (size_t)blockIdx.x * WTBLK + (size_t)(w * 9) * 512
                        + (size_t)lane * 8;
    const int kst = (n0 >> 5) * 512;
    const int qtp = ((n0 & 31) + lr) >> 3;
    const int eo  = lr & 7;

    const int QA = w;
    const bool hasB = (w == 0);
    const int QB = 4;

    float cregA[4], cregB[4];
#pragma unroll
    for (int rr = 0; rr < 4; ++rr) {
        cregA[rr] = jok ? Cst[(size_t)(QA * 16 + q * 4 + rr) * KH + jc] : 0.f;
        cregB[rr] = (hasB && jok) ? Cst[(size_t)(QB * 16 + q * 4 + rr) * KH + jc] : 0.f;
    }

    for (int t = 0; t < SEQL; ++t) {
        const bf16* Hin = t ? (HA + (size_t)(t - 1) * HSLAB) : H0;
        bf16*       HAt = HA + (size_t)t * HSLAB;
        const bf16* hb  = Hin + (size_t)(w * 9) * 512 + (size_t)lane * 8;

        // ---- burst loads: 36 W + 45 H fragments (contiguous 1KB each) ----
        bf16x8 bfr[4][9], a[5][9];
#pragma unroll
        for (int s = 0; s < 4; ++s)
#pragma unroll
            for (int k = 0; k < 9; ++k)
                bfr[s][k] = *(const bf16x8*)(wtb + (size_t)(s * 36 + k) * 512);
#pragma unroll
        for (int mi = 0; mi < 5; ++mi)
#pragma unroll
            for (int k = 0; k < 9; ++k)
                a[mi][k] = *(const bf16x8*)(hb + (size_t)(mi * 36 + k) * 512);

        // ---- G(t) -> LDS async (no registers); drains under MFMA ----
        float gpA[16], gpB[16];
        if constexpr (GF32) {
            const float* gsrc = (const float*)G + (size_t)t * BAT * N4P;
#pragma unroll
            for (int s = 0; s < 4; ++s)
#pragma unroll
                for (int rr = 0; rr < 4; ++rr)
                    gload_lds4(gsrc + (size_t)(QA * 16 + q * 4 + rr) * N4P + s * HIDD + jc,
                               &gl[w][s * 4 + rr][0]);
            if (hasB) {
#pragma unroll
                for (int s = 0; s < 4; ++s)
#pragma unroll
                    for (int rr = 0; rr < 4; ++rr)
                        gload_lds4(gsrc + (size_t)(QB * 16 + q * 4 + rr) * N4P + s * HIDD + jc,
                                   &gl[4][s * 4 + rr][0]);
            }
        } else {
            const GT* gsrc = G + (size_t)t * BAT * N4P;
#pragma unroll
            for (int s = 0; s < 4; ++s)
#pragma unroll
                for (int rr = 0; rr < 4; ++rr) {
                    gpA[s * 4 + rr] = jok ? (float)gsrc[(size_t)(QA * 16 + q * 4 + rr) * N4P + s * HIDD + jc] : 0.f;
                    gpB[s * 4 + rr] = (hasB && jok) ? (float)gsrc[(size_t)(QB * 16 + q * 4 + rr) * N4P + s * HIDD + jc] : 0.f;
                }
        }

        // ---- 180 MFMAs ----
        f32x4 acc[4][5] = {};
#pragma unroll
        for (int mi = 0; mi < 5; ++mi)
#pragma unroll
            for (int k = 0; k < 9; ++k)
#pragma unroll
                for (int s = 0; s < 4; ++s)
                    acc[s][mi] = __builtin_amdgcn_mfma_f32_16x16x32_bf16(
                        a[mi][k], bfr[s][k], acc[s][mi], 0, 0, 0);

        // ---- cross-wave K-reduction ----
#pragma unroll
        for (int s = 0; s < 4; ++s)
#pragma unroll
            for (int mi = 0; mi < 5; ++mi)
                *(f32x4*)&pl4[w][s][mi][lane][0] = acc[s][mi];
        __syncthreads();
        if constexpr (GF32)
            asm volatile("s_waitcnt vmcnt(0)" ::: "memory");  // gl ready

        // ---- consume QA (all waves) + QB (wave 0) ----
        {
            f32x4 p[4];
#pragma unroll
            for (int s = 0; s < 4; ++s)
                p[s] = *(const f32x4*)&pl4[0][s][QA][lane][0]
                     + *(const f32x4*)&pl4[1][s][QA][lane][0]
                     + *(const f32x4*)&pl4[2][s][QA][lane][0]
                     + *(const f32x4*)&pl4[3][s][QA][lane][0];
            if (jok) {
#pragma unroll
                for (int rr = 0; rr < 4; ++rr) {
                    float g0 = GF32 ? gl[w][0 + rr][lane]  : gpA[0 + rr];
                    float g1 = GF32 ? gl[w][4 + rr][lane]  : gpA[4 + rr];
                    float g2 = GF32 ? gl[w][8 + rr][lane]  : gpA[8 + rr];
                    float g3 = GF32 ? gl[w][12 + rr][lane] : gpA[12 + rr];
                    float ii = fsig(p[0][rr] + g0);
                    float ff = fsig(p[1][rr] + g1);
                    float oo = fsig(p[2][rr] + g2);
                    float gg = ftanh(p[3][rr] + g3);
                    float cn = ff * cregA[rr] + ii * gg;
                    cregA[rr] = cn;
                    bf16 hv = (bf16)(oo * ftanh(cn));
                    store_h_sc1(HAt + (size_t)QA * 18432 + kst + qtp * 128 + (q * 4 + rr) * 8 + eo,
                                (uint32_t)__builtin_bit_cast(unsigned short, hv));
                }
            }
        }
        if (hasB) {
            f32x4 p[4];
#pragma unroll
            for (int s = 0; s < 4; ++s)
                p[s] = *(const f32x4*)&pl4[0][s][QB][lane][0]
                     + *(const f32x4*)&pl4[1][s][QB][lane][0]
                     + *(const f32x4*)&pl4[2][s][QB][lane][0]
                     + *(const f32x4*)&pl4[3][s][QB][lane][0];
            if (jok) {
#pragma unroll
                for (int rr = 0; rr < 4; ++rr) {
                    float g0 = GF32 ? gl[4][0 + rr][lane]  : gpB[0 + rr];
                    float g1 = GF32 ? gl[4][4 + rr][lane]  : gpB[4 + rr];
                    float g2 = GF32 ? gl[4][8 + rr][lane]  : gpB[8 + rr];
                    float g3 = GF32 ? gl[4][12 + rr][lane] : gpB[12 + rr];
                    float ii = fsig(p[0][rr] + g0);
                    float ff = fsig(p[1][rr] + g1);
                    float oo = fsig(p[2][rr] + g2);
                    float gg = ftanh(p[3][rr] + g3);
                    float cn = ff * cregB[rr] + ii * gg;
                    cregB[rr] = cn;
                    bf16 hv = (bf16)(oo * ftanh(cn));
                    store_h_sc1(HAt + (size_t)QB * 18432 + kst + qtp * 128 + (q * 4 + rr) * 8 + eo,
                                (uint32_t)__builtin_bit_cast(unsigned short, hv));
                }
            }
        }

        if (t < SEQL - 1) {
            asm volatile("s_waitcnt vmcnt(0)" ::: "memory");  // H stores at L3
            gridbar(ctr, NBLK * (t + 1));
        }
    }

    if (jok) {
#pragma unroll
        for (int rr = 0; rr < 4; ++rr)
            Cst[(size_t)(QA * 16 + q * 4 + rr) * KH + jc] = cregA[rr];
        if (hasB) {
#pragma unroll
            for (int rr = 0; rr < 4; ++rr)
                Cst[(size_t)(QB * 16 + q * 4 + rr) * KH + jc] = cregB[rr];
        }
    }
}

__global__ void bar_reset(int* ctr) { if (threadIdx.x == 0) *ctr = 0; }

// ---------------------------------------------------------------------------
// Prep kernels (unchanged from r11)
// ---------------------------------------------------------------------------
__global__ void pad_wtB(const void* __restrict__ src, bf16* __restrict__ dst,
                        int N, int K, int NB, int KC, const int* __restrict__ dflag)
{
    const int f32w = *dflag;
    size_t total = (size_t)NB * KC * 512;
    for (size_t i = (size_t)blockIdx.x * blockDim.x + threadIdx.x; i < total;
         i += (size_t)gridDim.x * blockDim.x) {
        int o  = (int)(i & 511);
        size_t ci = i >> 9;
        int kc = (int)(ci % KC);
        int nb = (int)(ci / KC);
        int kq = o >> 7, r16 = (o >> 3) & 15, e = o & 7;
        int n = nb * 16 + r16;
        int c = kc * 32 + kq * 8 + e;
        dst[i] = (n < N && c < K) ? (bf16)ld_in(src, (size_t)n * K + c, f32w)
                                  : (bf16)0.f;
    }
}

__global__ void pad_wt(const void* __restrict__ src, bf16* __restrict__ dst,
                       const int* __restrict__ dflag)
{
    const int f32w = *dflag;
    const size_t total = (size_t)NBLK * WTBLK;
    for (size_t i = (size_t)blockIdx.x * blockDim.x + threadIdx.x; i < total;
         i += (size_t)gridDim.x * blockDim.x) {
        int e  = (int)(i & 7);
        int ln = (int)((i >> 3) & 63);
        size_t tile = i >> 9;
        int kg = (int)(tile % 36);
        size_t sb = tile / 36;
        int s   = (int)(sb & 3);
        int blk = (int)(sb >> 2);
        int jr  = blk * 16 + (ln & 15);
        int col = kg * 32 + (ln >> 4) * 8 + e;
        bf16 v = (bf16)0.f;
        if (jr < HIDD && col < HIDD)
            v = (bf16)ld_in(src, (size_t)(s * HIDD + jr) * HIDD + col, f32w);
        dst[i] = v;
    }
}

__global__ void combine_bias(const void* a, const void* b, float* o, int n, int np,
                             const int* __restrict__ dflag)
{
    const int f32w = *dflag;
    int i = blockIdx.x * blockDim.x + threadIdx.x;
    if (i < np) o[i] = (i < n) ? ld_in(a, i, f32w) + ld_in(b, i, f32w) : 0.f;
}

__global__ void cvt_bias(const void* a, float* o, int n, int np,
                         const int* __restrict__ dflag)
{
    const int f32w = *dflag;
    int i = blockIdx.x * blockDim.x + threadIdx.x;
    if (i < np) o[i] = (i < n) ? ld_in(a, i, f32w) : 0.f;
}

__global__ void embed_gather(const int* __restrict__ x, const void* __restrict__ emb,
                             bf16* __restrict__ XE, const int* __restrict__ dflag)
{
    const int f32w = *dflag;
    int row = blockIdx.x;                       // t*80+b
    int xi  = x[row];
    int b   = row % 80;
    bf16* base = XE + (size_t)(row / 80) * XSLAB;
    for (int c = threadIdx.x; c < KE; c += blockDim.x) {
        float v = (c < EMBD) ? ld_in(emb, (size_t)xi * EMBD + c, f32w) : 0.f;
        base[tflat(b, c, KC_E)] = (bf16)v;
    }
}

__global__ void zero_ha_pad(bf16* HA)
{
    int i = blockIdx.x * blockDim.x + threadIdx.x;
    if (i < MALL * 2) {
        int r = i >> 1;
        int t = r / BAT, b = r - t * BAT;
        int j = HIDD + (i & 1);
        HA[(size_t)t * HSLAB + tflat(b, j, KC_H)] = (bf16)0.f;
    }
}

__global__ void init_state(const void* __restrict__ h0, const void* __restrict__ c0,
                           size_t lofs, bf16* H0buf, float* Cst,
                           const int* __restrict__ dflag)
{
    const int f32w = *dflag;
    int i = blockIdx.x * blockDim.x + threadIdx.x;
    if (i >= BAT * KH) return;
    int b = i / KH, j = i % KH;
    float hv = 0.f, cv = 0.f;
    if (j < HIDD) {
        hv = ld_in(h0, lofs + (size_t)b * HIDD + j, f32w);
        cv = ld_in(c0, lofs + (size_t)b * HIDD + j, f32w);
    }
    H0buf[tflat(b, j, KC_H)] = (bf16)hv;
    Cst[i] = cv;
}

__global__ void write_tail(const bf16* __restrict__ Hfin, const float* __restrict__ Cfin,
                           void* __restrict__ outBase, size_t hOfs, size_t cOfs,
                           const int* __restrict__ dflag)
{
    const int f32w = *dflag;
    int i = blockIdx.x * blockDim.x + threadIdx.x;
    if (i >= BAT * HIDD) return;
    int b = i / HIDD, j = i % HIDD;
    float hv = clampdiag((float)Hfin[tflat(b, j, KC_H)]);
    float cv = clampdiag(Cfin[b * KH + j]);
    if (f32w) {
        ((float*)outBase)[hOfs + i] = hv;
        ((float*)outBase)[cOfs + i] = cv;
    } else {
        ((bf16*)outBase)[hOfs + i] = (bf16)hv;
        ((bf16*)outBase)[cOfs + i] = (bf16)cv;
    }
}

__global__ void sentinel_kernel(void* out, float v, const int* __restrict__ dflag)
{
    if (blockIdx.x == 0 && threadIdx.x == 0) {
        if (*dflag) ((float*)out)[0] = v;
        else        ((bf16*)out)[0] = (bf16)v;
    }
}

// ---------------------------------------------------------------------------
extern "C" void kernel_launch(void* const* d_in, const int* in_sizes, int n_in,
                              void* d_out, int out_size, void* d_ws, size_t ws_size,
                              hipStream_t stream)
{
    const int*  x    = (const int*)d_in[0];
    const void* h0   = d_in[1];
    const void* c0   = d_in[2];
    const void* emb  = d_in[3];
    const void* wih[3] = {d_in[4], d_in[8],  d_in[12]};
    const void* bih[3] = {d_in[5], d_in[9],  d_in[13]};
    const void* whh[3] = {d_in[6], d_in[10], d_in[14]};
    const void* bhh[3] = {d_in[7], d_in[11], d_in[15]};
    const void* wdec = d_in[16];
    const void* bdec = d_in[17];
    const size_t DEC = (size_t)MALL * NTOKV;
    (void)in_sizes; (void)n_in; (void)out_size;

    auto al = [](size_t v) { return (v + 255) & ~(size_t)255; };
    const size_t wdecB = al((size_t)NVP * KH * 2);
    auto plan = [&](bool gbf, size_t* offs) -> size_t {
        size_t off = 0;
        auto carve = [&](size_t b) { size_t p = off; off += al(b); return p; };
        offs[0] = carve((size_t)MALL * N4P * (gbf ? 2 : 4));     // G
        offs[1] = carve((size_t)MALL * KE * 2);                  // XE tiled
        offs[2] = carve((size_t)N4P * KH * 2);                   // WihP tiled
        offs[3] = carve((size_t)NBLK * WTBLK * 2);               // WT
        if (off < wdecB) off = wdecB;
        offs[4] = carve((size_t)MALL * KH * 2);                  // HA tiled
        offs[5] = carve((size_t)N4P * 4);                        // bc
        offs[6] = carve((size_t)NVP * 4);                        // bd
        offs[7] = carve((size_t)BAT * KH * 2);                   // H0 tiled
        offs[8] = carve((size_t)BAT * KH * 4);                   // Cst
        offs[9] = carve(256);                                    // dflag + barrier
        return off;
    };
    size_t offs[10];
    size_t needA = plan(false, offs);
    size_t needB = plan(true, offs);
    bool gbf16;
    if (ws_size >= needA)      { gbf16 = false; plan(false, offs); }
    else if (ws_size >= needB) { gbf16 = true;  plan(true,  offs); }
    else {
        int* dflag = (int*)d_ws;
        detect_dtype<<<1, 256, 0, stream>>>(emb, dflag);
        float mb = (float)(ws_size >> 20);
        if (mb > 20000.f) mb = 20000.f;
        sentinel_kernel<<<1, 64, 0, stream>>>(d_out, 700.f + mb, dflag);
        return;
    }

    char* ws = (char*)d_ws;
    void* G      = ws + offs[0];
    bf16* XE     = (bf16*)(ws + offs[1]);
    bf16* WihP   = (bf16*)(ws + offs[2]);
    bf16* WT     = (bf16*)(ws + offs[3]);
    bf16* WdecP  = (bf16*)(ws + 0);
    bf16* HA     = (bf16*)(ws + offs[4]);
    float* bc    = (float*)(ws + offs[5]);
    float* bd    = (float*)(ws + offs[6]);
    bf16* H0buf  = (bf16*)(ws + offs[7]);
    float* Cst   = (float*)(ws + offs[8]);
    int*  dflag  = (int*)(ws + offs[9]);
    int*  barctr = (int*)(ws + offs[9] + 128);

    detect_dtype<<<1, 256, 0, stream>>>(emb, dflag);
    embed_gather<<<MALL, 128, 0, stream>>>(x, emb, XE, dflag);
    zero_ha_pad<<<(MALL * 2 + 255) / 256, 256, 0, stream>>>(HA);

    for (int l = 0; l < 3; ++l) {
        int Kin = (l == 0) ? EMBD : HIDD;
        int kc  = (l == 0) ? KC_E : KC_H;
        int asl = (l == 0) ? XSLAB : HSLAB;
        pad_wtB<<<2048, 256, 0, stream>>>(wih[l], WihP, GATES, Kin, N4P / 16, kc, dflag);
        pad_wt<<<2048, 256, 0, stream>>>(whh[l], WT, dflag);
        combine_bias<<<(N4P + 255) / 256, 256, 0, stream>>>(bih[l], bhh[l], bc, GATES, N4P, dflag);
        init_state<<<(BAT * KH + 255) / 256, 256, 0, stream>>>(
            h0, c0, (size_t)l * BAT * HIDD, H0buf, Cst, dflag);
        bar_reset<<<1, 64, 0, stream>>>(barctr);
        const bf16* Ain = (l == 0) ? XE : HA;
        {
            int gx = N4P / 128, gy = (MALL + 127) / 128;
            gemm_bt<<<gx * gy, 256, 0, stream>>>(
                Ain, kc, asl, WihP, bc, G, N4P, MALL, N4P,
                gbf16 ? 1 : 0, dflag, gx, gy);
        }
        if (gbf16)
            lstm_layer<bf16><<<NBLK, 256, 0, stream>>>(
                WT, (const bf16*)G, H0buf, Cst, HA, barctr);
        else
            lstm_layer<float><<<NBLK, 256, 0, stream>>>(
                WT, (const float*)G, H0buf, Cst, HA, barctr);
        write_tail<<<(BAT * HIDD + 255) / 256, 256, 0, stream>>>(
            HA + (size_t)(SEQL - 1) * HSLAB, Cst, d_out,
            DEC + (size_t)l * BAT * HIDD,
            DEC + (size_t)3 * BAT * HIDD + (size_t)l * BAT * HIDD, dflag);
    }

    pad_wtB<<<4096, 256, 0, stream>>>(wdec, WdecP, NTOKV, HIDD, NVP / 16, KC_H, dflag);
    cvt_bias<<<(NVP + 255) / 256, 256, 0, stream>>>(bdec, bd, NTOKV, NVP, dflag);
    {
        int gx = NVP / 128, gy = (MALL + 127) / 128;
        gemm_bt<<<gx * gy, 256, 0, stream>>>(
            HA, KC_H, HSLAB, WdecP, bd, d_out, NTOKV, MALL, NTOKV, 2, dflag, gx, gy);
    }
}

// Round 13
// 2968.670 us; speedup vs baseline: 1.5786x; 1.0096x over previous
//
#include <hip/hip_runtime.h>
#include <stdint.h>
#include <math.h>

// Problem dims
#define SEQL 70
#define BAT 80
#define EMBD 400
#define HIDD 1150
#define GATES 4600        // 4*HIDD
#define NTOKV 33278
#define MALL 5600         // SEQL*BAT
// Padded dims
#define KH 1152
#define KE 416
#define N4P 4608
#define NVP 33280
// persistent LSTM kernel
#define NBLK 72
// fragment-tiled layouts: chunk(rowblock rb, kchunk kc) = (rb*KC + kc)*512,
// within-chunk offset for (row b, col c): ((c>>3)&3)*128 + (b&15)*8 + (c&7)
#define KC_H 36
#define HSLAB (80 * KH)       // 92160 el per t-slab (5 rowblocks x 36 x 512)
#define KC_E 13
#define XSLAB (80 * KE)       // 33280
#define WTBLK (4 * 36 * 512)  // lstm per-j-block W copy

typedef __bf16 bf16;
typedef bf16 bf16x8 __attribute__((ext_vector_type(8)));
typedef float f32x4 __attribute__((ext_vector_type(4)));

__device__ __forceinline__ float ld_in(const void* p, size_t i, int f32w) {
    return f32w ? ((const float*)p)[i] : (float)((const bf16*)p)[i];
}
__device__ __forceinline__ float clampdiag(float v) {
    return fminf(fmaxf(v, -30000.f), 30000.f);
}
__device__ __forceinline__ void store_h_sc1(bf16* addr, uint32_t bits) {
    asm volatile("global_store_short %0, %1, off sc0 sc1"
                 :: "v"(addr), "v"(bits) : "memory");
}
// async global->LDS: dest = wave-uniform base + lane*width; global src per-lane.
__device__ __forceinline__ void gload_lds16(const bf16* g, bf16* l) {
    __builtin_amdgcn_global_load_lds(
        (const __attribute__((address_space(1))) void*)g,
        (__attribute__((address_space(3))) void*)l, 16, 0, 0);
}
__device__ __forceinline__ void gload_lds4(const float* g, float* l) {
    __builtin_amdgcn_global_load_lds(
        (const __attribute__((address_space(1))) void*)g,
        (__attribute__((address_space(3))) void*)l, 4, 0, 0);
}
__device__ __forceinline__ size_t tflat(int b, int c, int KC) {
    return (size_t)(b >> 4) * KC * 512 + (size_t)(c >> 5) * 512
         + (size_t)((c >> 3) & 3) * 128 + (size_t)(b & 15) * 8 + (c & 7);
}
// fast gates: |err| ~1e-6 relative, safe at extremes
__device__ __forceinline__ float fsig(float x) { return 1.f / (1.f + __expf(-x)); }
__device__ __forceinline__ float ftanh(float x) {
    float e = __expf(-2.f * fabsf(x));
    float r = (1.f - e) / (1.f + e);
    return copysignf(r, x);
}

// ---------------------------------------------------------------------------
__global__ void detect_dtype(const void* __restrict__ emb, int* __restrict__ flag)
{
    __shared__ int fails;
    if (threadIdx.x == 0) fails = 0;
    __syncthreads();
    const uint32_t* w = (const uint32_t*)emb;
    int f = 0;
    for (int i = threadIdx.x; i < 1024; i += blockDim.x) {
        uint32_t h0 = w[i] & 0xFFFFu;
        uint32_t e0 = (h0 >> 7) & 0xFFu;
        if (e0 > 122u) f++;
    }
    atomicAdd(&fails, f);
    __syncthreads();
    if (threadIdx.x == 0) *flag = (fails > 100) ? 1 : 0;
}

// ---------------------------------------------------------------------------
// GEMM v3: tiled A/B + global_load_lds staging + 2-PHASE DOUBLE BUFFER.
// Per iter: issue STAGE(kc+1 -> buf^1) first, compute on buf[cur], then one
// vmcnt(0)+barrier. Staging latency hides under ds_read+MFMA.
// ---------------------------------------------------------------------------
__global__ __launch_bounds__(256)
void gemm_bt(const bf16* __restrict__ A, int KC, int ASLAB,
             const bf16* __restrict__ Bt,
             const float* __restrict__ bias,
             void* __restrict__ Cp, long long ldc,
             int M, int Nout, int outMode, const int* __restrict__ dflag,
             int gx, int gy)
{
    __shared__ __align__(16) bf16 As[2][8 * 512];
    __shared__ __align__(16) bf16 Bs[2][8 * 512];
    const int f32w = *dflag;
    const int tid  = threadIdx.x;
    const int lane = tid & 63;
    const int w    = tid >> 6;

    const int Wb = 32;
    int id = blockIdx.x;
    int fullb = gx / Wb, tw = gx - fullb * Wb;
    int bx, by;
    if (id < fullb * Wb * gy) {
        int band = id / (Wb * gy), wi = id % (Wb * gy);
        bx = band * Wb + wi % Wb;
        by = wi / Wb;
    } else {
        int wi = id - fullb * Wb * gy;
        bx = fullb * Wb + wi % tw;
        by = wi / tw;
    }
    const int bm = by * 128;
    const int bn = bx * 128;

    const int c0 = 2 * w, c1 = 2 * w + 1;
    const int maxrb = M / 16 - 1;
    const int rA0 = min(by * 8 + c0, maxrb);
    const int rA1 = min(by * 8 + c1, maxrb);
    const bf16* gA0 = A + (size_t)(rA0 / 5) * ASLAB + (size_t)(rA0 % 5) * KC * 512 + (size_t)lane * 8;
    const bf16* gA1 = A + (size_t)(rA1 / 5) * ASLAB + (size_t)(rA1 % 5) * KC * 512 + (size_t)lane * 8;
    const bf16* gB0 = Bt + (size_t)(bn / 16 + c0) * KC * 512 + (size_t)lane * 8;
    const bf16* gB1 = Bt + (size_t)(bn / 16 + c1) * KC * 512 + (size_t)lane * 8;

    const int ra = (w >> 1) * 4;
    const int rb = (w & 1) * 4;

    f32x4 acc[4][4] = {};

    // prologue: stage kc=0 into buf 0
    gload_lds16(gA0, &As[0][c0 * 512]);
    gload_lds16(gA1, &As[0][c1 * 512]);
    gload_lds16(gB0, &Bs[0][c0 * 512]);
    gload_lds16(gB1, &Bs[0][c1 * 512]);
    asm volatile("s_waitcnt vmcnt(0)" ::: "memory");
    __syncthreads();

    for (int kc = 0; kc < KC; ++kc) {
        const int cur = kc & 1;
        if (kc + 1 < KC) {   // issue next-tile stage before compute (T3)
            const int nxt = cur ^ 1;
            gload_lds16(gA0 + (size_t)(kc + 1) * 512, &As[nxt][c0 * 512]);
            gload_lds16(gA1 + (size_t)(kc + 1) * 512, &As[nxt][c1 * 512]);
            gload_lds16(gB0 + (size_t)(kc + 1) * 512, &Bs[nxt][c0 * 512]);
            gload_lds16(gB1 + (size_t)(kc + 1) * 512, &Bs[nxt][c1 * 512]);
        }
        bf16x8 af[4], bfv[4];
#pragma unroll
        for (int mi = 0; mi < 4; ++mi)
            af[mi] = *(const bf16x8*)&As[cur][(ra + mi) * 512 + lane * 8];
#pragma unroll
        for (int ni = 0; ni < 4; ++ni)
            bfv[ni] = *(const bf16x8*)&Bs[cur][(rb + ni) * 512 + lane * 8];
#pragma unroll
        for (int mi = 0; mi < 4; ++mi)
#pragma unroll
            for (int ni = 0; ni < 4; ++ni)
                acc[mi][ni] = __builtin_amdgcn_mfma_f32_16x16x32_bf16(
                    af[mi], bfv[ni], acc[mi][ni], 0, 0, 0);
        if (kc + 1 < KC) {
            asm volatile("s_waitcnt vmcnt(0)" ::: "memory");  // next buf landed
            __syncthreads();                                   // all waves done w/ cur
        }
    }

    const int wm = (w >> 1) * 64;
    const int wn = (w & 1) * 64;
    const int lr = lane & 15;
#pragma unroll
    for (int mi = 0; mi < 4; ++mi)
#pragma unroll
        for (int ni = 0; ni < 4; ++ni) {
            int n = bn + wn + ni * 16 + lr;
            if (n >= Nout) continue;
            float bv = bias[n];
#pragma unroll
            for (int rr = 0; rr < 4; ++rr) {
                int mm = bm + wm + mi * 16 + (lane >> 4) * 4 + rr;
                if (mm < M) {
                    float v = clampdiag(acc[mi][ni][rr] + bv);
                    size_t idx = (size_t)mm * ldc + n;
                    if (outMode == 0)      ((float*)Cp)[idx] = v;
                    else if (outMode == 1) ((bf16*)Cp)[idx] = (bf16)v;
                    else {
                        if (f32w) ((float*)Cp)[idx] = v;
                        else      ((bf16*)Cp)[idx] = (bf16)v;
                    }
                }
            }
        }
}

// ---------------------------------------------------------------------------
__device__ __forceinline__ void gridbar(int* ctr, int target)
{
    __syncthreads();
    if (threadIdx.x == 0) {
        atomicAdd(ctr, 1);
        int v;
        do {
            asm volatile("global_load_dword %0, %1, off sc0 sc1\n\t"
                         "s_waitcnt vmcnt(0)"
                         : "=v"(v) : "v"(ctr) : "memory");
        } while (v < target);
    }
    __syncthreads();
    asm volatile("" ::: "memory");
}

// ---------------------------------------------------------------------------
// Persistent per-layer LSTM v6 (validated r12 — unchanged).
// ---------------------------------------------------------------------------
template<typename GT>
__global__ __launch_bounds__(256, 1)
void lstm_layer(const bf16* __restrict__ WT,   // [72][4][36][512]
                const GT* __restrict__ G,      // [70][80][N4P]
                const bf16* __restrict__ H0,   // tiled slab
                float* __restrict__ Cst,       // [80][KH] row-major
                bf16* __restrict__ HA,         // [70] tiled slabs
                int* __restrict__ ctr)
{
    constexpr bool GF32 = (sizeof(GT) == 4);
    __shared__ __align__(16) float pl4[4][4][5][64][4];   // 80 KB
    __shared__ __align__(16) float gl[5][16][64];         // 20 KB
    const int tid  = threadIdx.x;
    const int lane = tid & 63;
    const int w    = tid >> 6;          // K-slice 0..3
    const int q    = lane >> 4;
    const int lr   = lane & 15;
    const int n0   = blockIdx.x * 16;
    const int jc   = n0 + lr;
    const bool jok = (jc < HIDD);

    const bf16* wtb = WT + (size_t)blockIdx.x * WTBLK + (size_t)(w * 9) * 512
                        + (size_t)lane * 8;
    const int kst = (n0 >> 5) * 512;
    const int qtp = ((n0 & 31) + lr) >> 3;
    const int eo  = lr & 7;

    const int QA = w;
    const bool hasB = (w == 0);
    const int QB = 4;

    float cregA[4], cregB[4];
#pragma unroll
    for (int rr = 0; rr < 4; ++rr) {
        cregA[rr] = jok ? Cst[(size_t)(QA * 16 + q * 4 + rr) * KH + jc] : 0.f;
        cregB[rr] = (hasB && jok) ? Cst[(size_t)(QB * 16 + q * 4 + rr) * KH + jc] : 0.f;
    }

    for (int t = 0; t < SEQL; ++t) {
        const bf16* Hin = t ? (HA + (size_t)(t - 1) * HSLAB) : H0;
        bf16*       HAt = HA + (size_t)t * HSLAB;
        const bf16* hb  = Hin + (size_t)(w * 9) * 512 + (size_t)lane * 8;

        // ---- burst loads: 36 W + 45 H fragments (contiguous 1KB each) ----
        bf16x8 bfr[4][9], a[5][9];
#pragma unroll
        for (int s = 0; s < 4; ++s)
#pragma unroll
            for (int k = 0; k < 9; ++k)
                bfr[s][k] = *(const bf16x8*)(wtb + (size_t)(s * 36 + k) * 512);
#pragma unroll
        for (int mi = 0; mi < 5; ++mi)
#pragma unroll
            for (int k = 0; k < 9; ++k)
                a[mi][k] = *(const bf16x8*)(hb + (size_t)(mi * 36 + k) * 512);

        // ---- G(t) -> LDS async (no registers); drains under MFMA ----
        float gpA[16], gpB[16];
        if constexpr (GF32) {
            const float* gsrc = (const float*)G + (size_t)t * BAT * N4P;
#pragma unroll
            for (int s = 0; s < 4; ++s)
#pragma unroll
                for (int rr = 0; rr < 4; ++rr)
                    gload_lds4(gsrc + (size_t)(QA * 16 + q * 4 + rr) * N4P + s * HIDD + jc,
                               &gl[w][s * 4 + rr][0]);
            if (hasB) {
#pragma unroll
                for (int s = 0; s < 4; ++s)
#pragma unroll
                    for (int rr = 0; rr < 4; ++rr)
                        gload_lds4(gsrc + (size_t)(QB * 16 + q * 4 + rr) * N4P + s * HIDD + jc,
                                   &gl[4][s * 4 + rr][0]);
            }
        } else {
            const GT* gsrc = G + (size_t)t * BAT * N4P;
#pragma unroll
            for (int s = 0; s < 4; ++s)
#pragma unroll
                for (int rr = 0; rr < 4; ++rr) {
                    gpA[s * 4 + rr] = jok ? (float)gsrc[(size_t)(QA * 16 + q * 4 + rr) * N4P + s * HIDD + jc] : 0.f;
                    gpB[s * 4 + rr] = (hasB && jok) ? (float)gsrc[(size_t)(QB * 16 + q * 4 + rr) * N4P + s * HIDD + jc] : 0.f;
                }
        }

        // ---- 180 MFMAs ----
        f32x4 acc[4][5] = {};
#pragma unroll
        for (int mi = 0; mi < 5; ++mi)
#pragma unroll
            for (int k = 0; k < 9; ++k)
#pragma unroll
                for (int s = 0; s < 4; ++s)
                    acc[s][mi] = __builtin_amdgcn_mfma_f32_16x16x32_bf16(
                        a[mi][k], bfr[s][k], acc[s][mi], 0, 0, 0);

        // ---- cross-wave K-reduction ----
#pragma unroll
        for (int s = 0; s < 4; ++s)
#pragma unroll
            for (int mi = 0; mi < 5; ++mi)
                *(f32x4*)&pl4[w][s][mi][lane][0] = acc[s][mi];
        __syncthreads();
        if constexpr (GF32)
            asm volatile("s_waitcnt vmcnt(0)" ::: "memory");  // gl ready

        // ---- consume QA (all waves) + QB (wave 0) ----
        {
            f32x4 p[4];
#pragma unroll
            for (int s = 0; s < 4; ++s)
                p[s] = *(const f32x4*)&pl4[0][s][QA][lane][0]
                     + *(const f32x4*)&pl4[1][s][QA][lane][0]
                     + *(const f32x4*)&pl4[2][s][QA][lane][0]
                     + *(const f32x4*)&pl4[3][s][QA][lane][0];
            if (jok) {
#pragma unroll
                for (int rr = 0; rr < 4; ++rr) {
                    float g0 = GF32 ? gl[w][0 + rr][lane]  : gpA[0 + rr];
                    float g1 = GF32 ? gl[w][4 + rr][lane]  : gpA[4 + rr];
                    float g2 = GF32 ? gl[w][8 + rr][lane]  : gpA[8 + rr];
                    float g3 = GF32 ? gl[w][12 + rr][lane] : gpA[12 + rr];
                    float ii = fsig(p[0][rr] + g0);
                    float ff = fsig(p[1][rr] + g1);
                    float oo = fsig(p[2][rr] + g2);
                    float gg = ftanh(p[3][rr] + g3);
                    float cn = ff * cregA[rr] + ii * gg;
                    cregA[rr] = cn;
                    bf16 hv = (bf16)(oo * ftanh(cn));
                    store_h_sc1(HAt + (size_t)QA * 18432 + kst + qtp * 128 + (q * 4 + rr) * 8 + eo,
                                (uint32_t)__builtin_bit_cast(unsigned short, hv));
                }
            }
        }
        if (hasB) {
            f32x4 p[4];
#pragma unroll
            for (int s = 0; s < 4; ++s)
                p[s] = *(const f32x4*)&pl4[0][s][QB][lane][0]
                     + *(const f32x4*)&pl4[1][s][QB][lane][0]
                     + *(const f32x4*)&pl4[2][s][QB][lane][0]
                     + *(const f32x4*)&pl4[3][s][QB][lane][0];
            if (jok) {
#pragma unroll
                for (int rr = 0; rr < 4; ++rr) {
                    float g0 = GF32 ? gl[4][0 + rr][lane]  : gpB[0 + rr];
                    float g1 = GF32 ? gl[4][4 + rr][lane]  : gpB[4 + rr];
                    float g2 = GF32 ? gl[4][8 + rr][lane]  : gpB[8 + rr];
                    float g3 = GF32 ? gl[4][12 + rr][lane] : gpB[12 + rr];
                    float ii = fsig(p[0][rr] + g0);
                    float ff = fsig(p[1][rr] + g1);
                    float oo = fsig(p[2][rr] + g2);
                    float gg = ftanh(p[3][rr] + g3);
                    float cn = ff * cregB[rr] + ii * gg;
                    cregB[rr] = cn;
                    bf16 hv = (bf16)(oo * ftanh(cn));
                    store_h_sc1(HAt + (size_t)QB * 18432 + kst + qtp * 128 + (q * 4 + rr) * 8 + eo,
                                (uint32_t)__builtin_bit_cast(unsigned short, hv));
                }
            }
        }

        if (t < SEQL - 1) {
            asm volatile("s_waitcnt vmcnt(0)" ::: "memory");  // H stores at L3
            gridbar(ctr, NBLK * (t + 1));
        }
    }

    if (jok) {
#pragma unroll
        for (int rr = 0; rr < 4; ++rr)
            Cst[(size_t)(QA * 16 + q * 4 + rr) * KH + jc] = cregA[rr];
        if (hasB) {
#pragma unroll
            for (int rr = 0; rr < 4; ++rr)
                Cst[(size_t)(QB * 16 + q * 4 + rr) * KH + jc] = cregB[rr];
        }
    }
}

__global__ void bar_reset(int* ctr) { if (threadIdx.x == 0) *ctr = 0; }

// ---------------------------------------------------------------------------
// Prep kernels (unchanged)
// ---------------------------------------------------------------------------
__global__ void pad_wtB(const void* __restrict__ src, bf16* __restrict__ dst,
                        int N, int K, int NB, int KC, const int* __restrict__ dflag)
{
    const int f32w = *dflag;
    size_t total = (size_t)NB * KC * 512;
    for (size_t i = (size_t)blockIdx.x * blockDim.x + threadIdx.x; i < total;
         i += (size_t)gridDim.x * blockDim.x) {
        int o  = (int)(i & 511);
        size_t ci = i >> 9;
        int kc = (int)(ci % KC);
        int nb = (int)(ci / KC);
        int kq = o >> 7, r16 = (o >> 3) & 15, e = o & 7;
        int n = nb * 16 + r16;
        int c = kc * 32 + kq * 8 + e;
        dst[i] = (n < N && c < K) ? (bf16)ld_in(src, (size_t)n * K + c, f32w)
                                  : (bf16)0.f;
    }
}

__global__ void pad_wt(const void* __restrict__ src, bf16* __restrict__ dst,
                       const int* __restrict__ dflag)
{
    const int f32w = *dflag;
    const size_t total = (size_t)NBLK * WTBLK;
    for (size_t i = (size_t)blockIdx.x * blockDim.x + threadIdx.x; i < total;
         i += (size_t)gridDim.x * blockDim.x) {
        int e  = (int)(i & 7);
        int ln = (int)((i >> 3) & 63);
        size_t tile = i >> 9;
        int kg = (int)(tile % 36);
        size_t sb = tile / 36;
        int s   = (int)(sb & 3);
        int blk = (int)(sb >> 2);
        int jr  = blk * 16 + (ln & 15);
        int col = kg * 32 + (ln >> 4) * 8 + e;
        bf16 v = (bf16)0.f;
        if (jr < HIDD && col < HIDD)
            v = (bf16)ld_in(src, (size_t)(s * HIDD + jr) * HIDD + col, f32w);
        dst[i] = v;
    }
}

__global__ void combine_bias(const void* a, const void* b, float* o, int n, int np,
                             const int* __restrict__ dflag)
{
    const int f32w = *dflag;
    int i = blockIdx.x * blockDim.x + threadIdx.x;
    if (i < np) o[i] = (i < n) ? ld_in(a, i, f32w) + ld_in(b, i, f32w) : 0.f;
}

__global__ void cvt_bias(const void* a, float* o, int n, int np,
                         const int* __restrict__ dflag)
{
    const int f32w = *dflag;
    int i = blockIdx.x * blockDim.x + threadIdx.x;
    if (i < np) o[i] = (i < n) ? ld_in(a, i, f32w) : 0.f;
}

__global__ void embed_gather(const int* __restrict__ x, const void* __restrict__ emb,
                             bf16* __restrict__ XE, const int* __restrict__ dflag)
{
    const int f32w = *dflag;
    int row = blockIdx.x;                       // t*80+b
    int xi  = x[row];
    int b   = row % 80;
    bf16* base = XE + (size_t)(row / 80) * XSLAB;
    for (int c = threadIdx.x; c < KE; c += blockDim.x) {
        float v = (c < EMBD) ? ld_in(emb, (size_t)xi * EMBD + c, f32w) : 0.f;
        base[tflat(b, c, KC_E)] = (bf16)v;
    }
}

__global__ void zero_ha_pad(bf16* HA)
{
    int i = blockIdx.x * blockDim.x + threadIdx.x;
    if (i < MALL * 2) {
        int r = i >> 1;
        int t = r / BAT, b = r - t * BAT;
        int j = HIDD + (i & 1);
        HA[(size_t)t * HSLAB + tflat(b, j, KC_H)] = (bf16)0.f;
    }
}

__global__ void init_state(const void* __restrict__ h0, const void* __restrict__ c0,
                           size_t lofs, bf16* H0buf, float* Cst,
                           const int* __restrict__ dflag)
{
    const int f32w = *dflag;
    int i = blockIdx.x * blockDim.x + threadIdx.x;
    if (i >= BAT * KH) return;
    int b = i / KH, j = i % KH;
    float hv = 0.f, cv = 0.f;
    if (j < HIDD) {
        hv = ld_in(h0, lofs + (size_t)b * HIDD + j, f32w);
        cv = ld_in(c0, lofs + (size_t)b * HIDD + j, f32w);
    }
    H0buf[tflat(b, j, KC_H)] = (bf16)hv;
    Cst[i] = cv;
}

__global__ void write_tail(const bf16* __restrict__ Hfin, const float* __restrict__ Cfin,
                           void* __restrict__ outBase, size_t hOfs, size_t cOfs,
                           const int* __restrict__ dflag)
{
    const int f32w = *dflag;
    int i = blockIdx.x * blockDim.x + threadIdx.x;
    if (i >= BAT * HIDD) return;
    int b = i / HIDD, j = i % HIDD;
    float hv = clampdiag((float)Hfin[tflat(b, j, KC_H)]);
    float cv = clampdiag(Cfin[b * KH + j]);
    if (f32w) {
        ((float*)outBase)[hOfs + i] = hv;
        ((float*)outBase)[cOfs + i] = cv;
    } else {
        ((bf16*)outBase)[hOfs + i] = (bf16)hv;
        ((bf16*)outBase)[cOfs + i] = (bf16)cv;
    }
}

__global__ void sentinel_kernel(void* out, float v, const int* __restrict__ dflag)
{
    if (blockIdx.x == 0 && threadIdx.x == 0) {
        if (*dflag) ((float*)out)[0] = v;
        else        ((bf16*)out)[0] = (bf16)v;
    }
}

// ---------------------------------------------------------------------------
extern "C" void kernel_launch(void* const* d_in, const int* in_sizes, int n_in,
                              void* d_out, int out_size, void* d_ws, size_t ws_size,
                              hipStream_t stream)
{
    const int*  x    = (const int*)d_in[0];
    const void* h0   = d_in[1];
    const void* c0   = d_in[2];
    const void* emb  = d_in[3];
    const void* wih[3] = {d_in[4], d_in[8],  d_in[12]};
    const void* bih[3] = {d_in[5], d_in[9],  d_in[13]};
    const void* whh[3] = {d_in[6], d_in[10], d_in[14]};
    const void* bhh[3] = {d_in[7], d_in[11], d_in[15]};
    const void* wdec = d_in[16];
    const void* bdec = d_in[17];
    const size_t DEC = (size_t)MALL * NTOKV;
    (void)in_sizes; (void)n_in; (void)out_size;

    auto al = [](size_t v) { return (v + 255) & ~(size_t)255; };
    const size_t wdecB = al((size_t)NVP * KH * 2);
    auto plan = [&](bool gbf, size_t* offs) -> size_t {
        size_t off = 0;
        auto carve = [&](size_t b) { size_t p = off; off += al(b); return p; };
        offs[0] = carve((size_t)MALL * N4P * (gbf ? 2 : 4));     // G
        offs[1] = carve((size_t)MALL * KE * 2);                  // XE tiled
        offs[2] = carve((size_t)N4P * KH * 2);                   // WihP tiled
        offs[3] = carve((size_t)NBLK * WTBLK * 2);               // WT
        if (off < wdecB) off = wdecB;
        offs[4] = carve((size_t)MALL * KH * 2);                  // HA tiled
        offs[5] = carve((size_t)N4P * 4);                        // bc
        offs[6] = carve((size_t)NVP * 4);                        // bd
        offs[7] = carve((size_t)BAT * KH * 2);                   // H0 tiled
        offs[8] = carve((size_t)BAT * KH * 4);                   // Cst
        offs[9] = carve(256);                                    // dflag + barrier
        return off;
    };
    size_t offs[10];
    size_t needA = plan(false, offs);
    size_t needB = plan(true, offs);
    bool gbf16;
    if (ws_size >= needA)      { gbf16 = false; plan(false, offs); }
    else if (ws_size >= needB) { gbf16 = true;  plan(true,  offs); }
    else {
        int* dflag = (int*)d_ws;
        detect_dtype<<<1, 256, 0, stream>>>(emb, dflag);
        float mb = (float)(ws_size >> 20);
        if (mb > 20000.f) mb = 20000.f;
        sentinel_kernel<<<1, 64, 0, stream>>>(d_out, 700.f + mb, dflag);
        return;
    }

    char* ws = (char*)d_ws;
    void* G      = ws + offs[0];
    bf16* XE     = (bf16*)(ws + offs[1]);
    bf16* WihP   = (bf16*)(ws + offs[2]);
    bf16* WT     = (bf16*)(ws + offs[3]);
    bf16* WdecP  = (bf16*)(ws + 0);
    bf16* HA     = (bf16*)(ws + offs[4]);
    float* bc    = (float*)(ws + offs[5]);
    float* bd    = (float*)(ws + offs[6]);
    bf16* H0buf  = (bf16*)(ws + offs[7]);
    float* Cst   = (float*)(ws + offs[8]);
    int*  dflag  = (int*)(ws + offs[9]);
    int*  barctr = (int*)(ws + offs[9] + 128);

    detect_dtype<<<1, 256, 0, stream>>>(emb, dflag);
    embed_gather<<<MALL, 128, 0, stream>>>(x, emb, XE, dflag);
    zero_ha_pad<<<(MALL * 2 + 255) / 256, 256, 0, stream>>>(HA);

    for (int l = 0; l < 3; ++l) {
        int Kin = (l == 0) ? EMBD : HIDD;
        int kc  = (l == 0) ? KC_E : KC_H;
        int asl = (l == 0) ? XSLAB : HSLAB;
        pad_wtB<<<2048, 256, 0, stream>>>(wih[l], WihP, GATES, Kin, N4P / 16, kc, dflag);
        pad_wt<<<2048, 256, 0, stream>>>(whh[l], WT, dflag);
        combine_bias<<<(N4P + 255) / 256, 256, 0, stream>>>(bih[l], bhh[l], bc, GATES, N4P, dflag);
        init_state<<<(BAT * KH + 255) / 256, 256, 0, stream>>>(
            h0, c0, (size_t)l * BAT * HIDD, H0buf, Cst, dflag);
        bar_reset<<<1, 64, 0, stream>>>(barctr);
        const bf16* Ain = (l == 0) ? XE : HA;
        {
            int gx = N4P / 128, gy = (MALL + 127) / 128;
            gemm_bt<<<gx * gy, 256, 0, stream>>>(
                Ain, kc, asl, WihP, bc, G, N4P, MALL, N4P,
                gbf16 ? 1 : 0, dflag, gx, gy);
        }
        if (gbf16)
            lstm_layer<bf16><<<NBLK, 256, 0, stream>>>(
                WT, (const bf16*)G, H0buf, Cst, HA, barctr);
        else
            lstm_layer<float><<<NBLK, 256, 0, stream>>>(
                WT, (const float*)G, H0buf, Cst, HA, barctr);
        write_tail<<<(BAT * HIDD + 255) / 256, 256, 0, stream>>>(
            HA + (size_t)(SEQL - 1) * HSLAB, Cst, d_out,
            DEC + (size_t)l * BAT * HIDD,
            DEC + (size_t)3 * BAT * HIDD + (size_t)l * BAT * HIDD, dflag);
    }

    pad_wtB<<<4096, 256, 0, stream>>>(wdec, WdecP, NTOKV, HIDD, NVP / 16, KC_H, dflag);
    cvt_bias<<<(NVP + 255) / 256, 256, 0, stream>>>(bdec, bd, NTOKV, NVP, dflag);
    {
        int gx = NVP / 128, gy = (MALL + 127) / 128;
        gemm_bt<<<gx * gy, 256, 0, stream>>>(
            HA, KC_H, HSLAB, WdecP, bd, d_out, NTOKV, MALL, NTOKV, 2, dflag, gx, gy);
    }
}

// Round 14
// 2962.086 us; speedup vs baseline: 1.5821x; 1.0022x over previous
//
#include <hip/hip_runtime.h>
#include <stdint.h>
#include <math.h>

// Problem dims
#define SEQL 70
#define BAT 80
#define EMBD 400
#define HIDD 1150
#define GATES 4600        // 4*HIDD
#define NTOKV 33278
#define MALL 5600         // SEQL*BAT
// Padded dims
#define KH 1152
#define KE 416
#define N4P 4608
#define NVP 33280
// persistent LSTM kernel
#define NBLK 72
// fragment-tiled layouts: chunk(rowblock rb, kchunk kc) = (rb*KC + kc)*512,
// within-chunk offset for (row b, col c): ((c>>3)&3)*128 + (b&15)*8 + (c&7)
#define KC_H 36
#define HSLAB (80 * KH)       // 92160 el per t-slab (5 rowblocks x 36 x 512)
#define KC_E 13
#define XSLAB (80 * KE)       // 33280
#define WTBLK (4 * 36 * 512)  // lstm per-j-block W copy

typedef __bf16 bf16;
typedef bf16 bf16x8 __attribute__((ext_vector_type(8)));
typedef float f32x4 __attribute__((ext_vector_type(4)));

__device__ __forceinline__ float ld_in(const void* p, size_t i, int f32w) {
    return f32w ? ((const float*)p)[i] : (float)((const bf16*)p)[i];
}
__device__ __forceinline__ float clampdiag(float v) {
    return fminf(fmaxf(v, -30000.f), 30000.f);
}
__device__ __forceinline__ void store_h_sc1(bf16* addr, uint32_t bits) {
    asm volatile("global_store_short %0, %1, off sc0 sc1"
                 :: "v"(addr), "v"(bits) : "memory");
}
// async global->LDS: dest = wave-uniform base + lane*width; global src per-lane.
__device__ __forceinline__ void gload_lds16(const bf16* g, bf16* l) {
    __builtin_amdgcn_global_load_lds(
        (const __attribute__((address_space(1))) void*)g,
        (__attribute__((address_space(3))) void*)l, 16, 0, 0);
}
__device__ __forceinline__ void gload_lds4(const float* g, float* l) {
    __builtin_amdgcn_global_load_lds(
        (const __attribute__((address_space(1))) void*)g,
        (__attribute__((address_space(3))) void*)l, 4, 0, 0);
}
__device__ __forceinline__ size_t tflat(int b, int c, int KC) {
    return (size_t)(b >> 4) * KC * 512 + (size_t)(c >> 5) * 512
         + (size_t)((c >> 3) & 3) * 128 + (size_t)(b & 15) * 8 + (c & 7);
}
// fast gates: |err| ~1e-6 relative, safe at extremes
__device__ __forceinline__ float fsig(float x) { return 1.f / (1.f + __expf(-x)); }
__device__ __forceinline__ float ftanh(float x) {
    float e = __expf(-2.f * fabsf(x));
    float r = (1.f - e) / (1.f + e);
    return copysignf(r, x);
}

// ---------------------------------------------------------------------------
__global__ void detect_dtype(const void* __restrict__ emb, int* __restrict__ flag)
{
    __shared__ int fails;
    if (threadIdx.x == 0) fails = 0;
    __syncthreads();
    const uint32_t* w = (const uint32_t*)emb;
    int f = 0;
    for (int i = threadIdx.x; i < 1024; i += blockDim.x) {
        uint32_t h0 = w[i] & 0xFFFFu;
        uint32_t e0 = (h0 >> 7) & 0xFFu;
        if (e0 > 122u) f++;
    }
    atomicAdd(&fails, f);
    __syncthreads();
    if (threadIdx.x == 0) *flag = (fails > 100) ? 1 : 0;
}

// ---------------------------------------------------------------------------
// GEMM v4: tiled A/B + global_load_lds + 3-BUFFER RING with counted vmcnt.
// At iter kc: buf[kc%3] ready, stage(kc+1) in flight, issue stage(kc+2);
// end-of-iter waits vmcnt(4) (= stage(kc+1) landed, kc+2 still flying).
// A tile's staging latency is hidden by one FULL iteration, not just the
// compute phase (r13 showed that phase is ~180cy vs ~450cy latency).
// ---------------------------------------------------------------------------
__global__ __launch_bounds__(256)
void gemm_bt(const bf16* __restrict__ A, int KC, int ASLAB,
             const bf16* __restrict__ Bt,
             const float* __restrict__ bias,
             void* __restrict__ Cp, long long ldc,
             int M, int Nout, int outMode, const int* __restrict__ dflag,
             int gx, int gy)
{
    __shared__ __align__(16) bf16 As[3][8 * 512];
    __shared__ __align__(16) bf16 Bs[3][8 * 512];
    const int f32w = *dflag;
    const int tid  = threadIdx.x;
    const int lane = tid & 63;
    const int w    = tid >> 6;

    const int Wb = 32;
    int id = blockIdx.x;
    int fullb = gx / Wb, tw = gx - fullb * Wb;
    int bx, by;
    if (id < fullb * Wb * gy) {
        int band = id / (Wb * gy), wi = id % (Wb * gy);
        bx = band * Wb + wi % Wb;
        by = wi / Wb;
    } else {
        int wi = id - fullb * Wb * gy;
        bx = fullb * Wb + wi % tw;
        by = wi / tw;
    }
    const int bm = by * 128;
    const int bn = bx * 128;

    const int c0 = 2 * w, c1 = 2 * w + 1;
    const int maxrb = M / 16 - 1;
    const int rA0 = min(by * 8 + c0, maxrb);
    const int rA1 = min(by * 8 + c1, maxrb);
    const bf16* gA0 = A + (size_t)(rA0 / 5) * ASLAB + (size_t)(rA0 % 5) * KC * 512 + (size_t)lane * 8;
    const bf16* gA1 = A + (size_t)(rA1 / 5) * ASLAB + (size_t)(rA1 % 5) * KC * 512 + (size_t)lane * 8;
    const bf16* gB0 = Bt + (size_t)(bn / 16 + c0) * KC * 512 + (size_t)lane * 8;
    const bf16* gB1 = Bt + (size_t)(bn / 16 + c1) * KC * 512 + (size_t)lane * 8;

    const int ra = (w >> 1) * 4;
    const int rb = (w & 1) * 4;

    f32x4 acc[4][4] = {};

    // prologue: stage kc=0,1 into bufs 0,1; wait for 0 only (vmcnt(4))
    auto stage = [&](int kc, int buf) {
        gload_lds16(gA0 + (size_t)kc * 512, &As[buf][c0 * 512]);
        gload_lds16(gA1 + (size_t)kc * 512, &As[buf][c1 * 512]);
        gload_lds16(gB0 + (size_t)kc * 512, &Bs[buf][c0 * 512]);
        gload_lds16(gB1 + (size_t)kc * 512, &Bs[buf][c1 * 512]);
    };
    stage(0, 0);
    if (KC > 1) {
        stage(1, 1);
        asm volatile("s_waitcnt vmcnt(4)" ::: "memory");
    } else {
        asm volatile("s_waitcnt vmcnt(0)" ::: "memory");
    }
    __syncthreads();

    for (int kc = 0; kc < KC; ++kc) {
        const int cur = kc % 3;
        if (kc + 2 < KC) stage(kc + 2, (kc + 2) % 3);
        bf16x8 af[4], bfv[4];
#pragma unroll
        for (int mi = 0; mi < 4; ++mi)
            af[mi] = *(const bf16x8*)&As[cur][(ra + mi) * 512 + lane * 8];
#pragma unroll
        for (int ni = 0; ni < 4; ++ni)
            bfv[ni] = *(const bf16x8*)&Bs[cur][(rb + ni) * 512 + lane * 8];
#pragma unroll
        for (int mi = 0; mi < 4; ++mi)
#pragma unroll
            for (int ni = 0; ni < 4; ++ni)
                acc[mi][ni] = __builtin_amdgcn_mfma_f32_16x16x32_bf16(
                    af[mi], bfv[ni], acc[mi][ni], 0, 0, 0);
        if (kc + 1 < KC) {
            if (kc + 2 < KC)
                asm volatile("s_waitcnt vmcnt(4)" ::: "memory");  // kc+1 landed
            else
                asm volatile("s_waitcnt vmcnt(0)" ::: "memory");
            __syncthreads();
        }
    }

    const int wm = (w >> 1) * 64;
    const int wn = (w & 1) * 64;
    const int lr = lane & 15;
#pragma unroll
    for (int mi = 0; mi < 4; ++mi)
#pragma unroll
        for (int ni = 0; ni < 4; ++ni) {
            int n = bn + wn + ni * 16 + lr;
            if (n >= Nout) continue;
            float bv = bias[n];
#pragma unroll
            for (int rr = 0; rr < 4; ++rr) {
                int mm = bm + wm + mi * 16 + (lane >> 4) * 4 + rr;
                if (mm < M) {
                    float v = clampdiag(acc[mi][ni][rr] + bv);
                    size_t idx = (size_t)mm * ldc + n;
                    if (outMode == 0)      ((float*)Cp)[idx] = v;
                    else if (outMode == 1) ((bf16*)Cp)[idx] = (bf16)v;
                    else {
                        if (f32w) ((float*)Cp)[idx] = v;
                        else      ((bf16*)Cp)[idx] = (bf16)v;
                    }
                }
            }
        }
}

// ---------------------------------------------------------------------------
__device__ __forceinline__ void gridbar(int* ctr, int target)
{
    __syncthreads();
    if (threadIdx.x == 0) {
        atomicAdd(ctr, 1);
        int v;
        do {
            asm volatile("global_load_dword %0, %1, off sc0 sc1\n\t"
                         "s_waitcnt vmcnt(0)"
                         : "=v"(v) : "v"(ctr) : "memory");
        } while (v < target);
    }
    __syncthreads();
    asm volatile("" ::: "memory");
}

// ---------------------------------------------------------------------------
// Persistent per-layer LSTM v6 (validated r12 — unchanged).
// ---------------------------------------------------------------------------
template<typename GT>
__global__ __launch_bounds__(256, 1)
void lstm_layer(const bf16* __restrict__ WT,   // [72][4][36][512]
                const GT* __restrict__ G,      // [70][80][N4P]
                const bf16* __restrict__ H0,   // tiled slab
                float* __restrict__ Cst,       // [80][KH] row-major
                bf16* __restrict__ HA,         // [70] tiled slabs
                int* __restrict__ ctr)
{
    constexpr bool GF32 = (sizeof(GT) == 4);
    __shared__ __align__(16) float pl4[4][4][5][64][4];   // 80 KB
    __shared__ __align__(16) float gl[5][16][64];         // 20 KB
    const int tid  = threadIdx.x;
    const int lane = tid & 63;
    const int w    = tid >> 6;          // K-slice 0..3
    const int q    = lane >> 4;
    const int lr   = lane & 15;
    const int n0   = blockIdx.x * 16;
    const int jc   = n0 + lr;
    const bool jok = (jc < HIDD);

    const bf16* wtb = WT + (size_t)blockIdx.x * WTBLK + (size_t)(w * 9) * 512
                        + (size_t)lane * 8;
    const int kst = (n0 >> 5) * 512;
    const int qtp = ((n0 & 31) + lr) >> 3;
    const int eo  = lr & 7;

    const int QA = w;
    const bool hasB = (w == 0);
    const int QB = 4;

    float cregA[4], cregB[4];
#pragma unroll
    for (int rr = 0; rr < 4; ++rr) {
        cregA[rr] = jok ? Cst[(size_t)(QA * 16 + q * 4 + rr) * KH + jc] : 0.f;
        cregB[rr] = (hasB && jok) ? Cst[(size_t)(QB * 16 + q * 4 + rr) * KH + jc] : 0.f;
    }

    for (int t = 0; t < SEQL; ++t) {
        const bf16* Hin = t ? (HA + (size_t)(t - 1) * HSLAB) : H0;
        bf16*       HAt = HA + (size_t)t * HSLAB;
        const bf16* hb  = Hin + (size_t)(w * 9) * 512 + (size_t)lane * 8;

        // ---- burst loads: 36 W + 45 H fragments (contiguous 1KB each) ----
        bf16x8 bfr[4][9], a[5][9];
#pragma unroll
        for (int s = 0; s < 4; ++s)
#pragma unroll
            for (int k = 0; k < 9; ++k)
                bfr[s][k] = *(const bf16x8*)(wtb + (size_t)(s * 36 + k) * 512);
#pragma unroll
        for (int mi = 0; mi < 5; ++mi)
#pragma unroll
            for (int k = 0; k < 9; ++k)
                a[mi][k] = *(const bf16x8*)(hb + (size_t)(mi * 36 + k) * 512);

        // ---- G(t) -> LDS async (no registers); drains under MFMA ----
        float gpA[16], gpB[16];
        if constexpr (GF32) {
            const float* gsrc = (const float*)G + (size_t)t * BAT * N4P;
#pragma unroll
            for (int s = 0; s < 4; ++s)
#pragma unroll
                for (int rr = 0; rr < 4; ++rr)
                    gload_lds4(gsrc + (size_t)(QA * 16 + q * 4 + rr) * N4P + s * HIDD + jc,
                               &gl[w][s * 4 + rr][0]);
            if (hasB) {
#pragma unroll
                for (int s = 0; s < 4; ++s)
#pragma unroll
                    for (int rr = 0; rr < 4; ++rr)
                        gload_lds4(gsrc + (size_t)(QB * 16 + q * 4 + rr) * N4P + s * HIDD + jc,
                                   &gl[4][s * 4 + rr][0]);
            }
        } else {
            const GT* gsrc = G + (size_t)t * BAT * N4P;
#pragma unroll
            for (int s = 0; s < 4; ++s)
#pragma unroll
                for (int rr = 0; rr < 4; ++rr) {
                    gpA[s * 4 + rr] = jok ? (float)gsrc[(size_t)(QA * 16 + q * 4 + rr) * N4P + s * HIDD + jc] : 0.f;
                    gpB[s * 4 + rr] = (hasB && jok) ? (float)gsrc[(size_t)(QB * 16 + q * 4 + rr) * N4P + s * HIDD + jc] : 0.f;
                }
        }

        // ---- 180 MFMAs ----
        f32x4 acc[4][5] = {};
#pragma unroll
        for (int mi = 0; mi < 5; ++mi)
#pragma unroll
            for (int k = 0; k < 9; ++k)
#pragma unroll
                for (int s = 0; s < 4; ++s)
                    acc[s][mi] = __builtin_amdgcn_mfma_f32_16x16x32_bf16(
                        a[mi][k], bfr[s][k], acc[s][mi], 0, 0, 0);

        // ---- cross-wave K-reduction ----
#pragma unroll
        for (int s = 0; s < 4; ++s)
#pragma unroll
            for (int mi = 0; mi < 5; ++mi)
                *(f32x4*)&pl4[w][s][mi][lane][0] = acc[s][mi];
        __syncthreads();
        if constexpr (GF32)
            asm volatile("s_waitcnt vmcnt(0)" ::: "memory");  // gl ready

        // ---- consume QA (all waves) + QB (wave 0) ----
        {
            f32x4 p[4];
#pragma unroll
            for (int s = 0; s < 4; ++s)
                p[s] = *(const f32x4*)&pl4[0][s][QA][lane][0]
                     + *(const f32x4*)&pl4[1][s][QA][lane][0]
                     + *(const f32x4*)&pl4[2][s][QA][lane][0]
                     + *(const f32x4*)&pl4[3][s][QA][lane][0];
            if (jok) {
#pragma unroll
                for (int rr = 0; rr < 4; ++rr) {
                    float g0 = GF32 ? gl[w][0 + rr][lane]  : gpA[0 + rr];
                    float g1 = GF32 ? gl[w][4 + rr][lane]  : gpA[4 + rr];
                    float g2 = GF32 ? gl[w][8 + rr][lane]  : gpA[8 + rr];
                    float g3 = GF32 ? gl[w][12 + rr][lane] : gpA[12 + rr];
                    float ii = fsig(p[0][rr] + g0);
                    float ff = fsig(p[1][rr] + g1);
                    float oo = fsig(p[2][rr] + g2);
                    float gg = ftanh(p[3][rr] + g3);
                    float cn = ff * cregA[rr] + ii * gg;
                    cregA[rr] = cn;
                    bf16 hv = (bf16)(oo * ftanh(cn));
                    store_h_sc1(HAt + (size_t)QA * 18432 + kst + qtp * 128 + (q * 4 + rr) * 8 + eo,
                                (uint32_t)__builtin_bit_cast(unsigned short, hv));
                }
            }
        }
        if (hasB) {
            f32x4 p[4];
#pragma unroll
            for (int s = 0; s < 4; ++s)
                p[s] = *(const f32x4*)&pl4[0][s][QB][lane][0]
                     + *(const f32x4*)&pl4[1][s][QB][lane][0]
                     + *(const f32x4*)&pl4[2][s][QB][lane][0]
                     + *(const f32x4*)&pl4[3][s][QB][lane][0];
            if (jok) {
#pragma unroll
                for (int rr = 0; rr < 4; ++rr) {
                    float g0 = GF32 ? gl[4][0 + rr][lane]  : gpB[0 + rr];
                    float g1 = GF32 ? gl[4][4 + rr][lane]  : gpB[4 + rr];
                    float g2 = GF32 ? gl[4][8 + rr][lane]  : gpB[8 + rr];
                    float g3 = GF32 ? gl[4][12 + rr][lane] : gpB[12 + rr];
                    float ii = fsig(p[0][rr] + g0);
                    float ff = fsig(p[1][rr] + g1);
                    float oo = fsig(p[2][rr] + g2);
                    float gg = ftanh(p[3][rr] + g3);
                    float cn = ff * cregB[rr] + ii * gg;
                    cregB[rr] = cn;
                    bf16 hv = (bf16)(oo * ftanh(cn));
                    store_h_sc1(HAt + (size_t)QB * 18432 + kst + qtp * 128 + (q * 4 + rr) * 8 + eo,
                                (uint32_t)__builtin_bit_cast(unsigned short, hv));
                }
            }
        }

        if (t < SEQL - 1) {
            asm volatile("s_waitcnt vmcnt(0)" ::: "memory");  // H stores at L3
            gridbar(ctr, NBLK * (t + 1));
        }
    }

    if (jok) {
#pragma unroll
        for (int rr = 0; rr < 4; ++rr)
            Cst[(size_t)(QA * 16 + q * 4 + rr) * KH + jc] = cregA[rr];
        if (hasB) {
#pragma unroll
            for (int rr = 0; rr < 4; ++rr)
                Cst[(size_t)(QB * 16 + q * 4 + rr) * KH + jc] = cregB[rr];
        }
    }
}

__global__ void bar_reset(int* ctr) { if (threadIdx.x == 0) *ctr = 0; }

// ---------------------------------------------------------------------------
// Prep kernels (unchanged)
// ---------------------------------------------------------------------------
__global__ void pad_wtB(const void* __restrict__ src, bf16* __restrict__ dst,
                        int N, int K, int NB, int KC, const int* __restrict__ dflag)
{
    const int f32w = *dflag;
    size_t total = (size_t)NB * KC * 512;
    for (size_t i = (size_t)blockIdx.x * blockDim.x + threadIdx.x; i < total;
         i += (size_t)gridDim.x * blockDim.x) {
        int o  = (int)(i & 511);
        size_t ci = i >> 9;
        int kc = (int)(ci % KC);
        int nb = (int)(ci / KC);
        int kq = o >> 7, r16 = (o >> 3) & 15, e = o & 7;
        int n = nb * 16 + r16;
        int c = kc * 32 + kq * 8 + e;
        dst[i] = (n < N && c < K) ? (bf16)ld_in(src, (size_t)n * K + c, f32w)
                                  : (bf16)0.f;
    }
}

__global__ void pad_wt(const void* __restrict__ src, bf16* __restrict__ dst,
                       const int* __restrict__ dflag)
{
    const int f32w = *dflag;
    const size_t total = (size_t)NBLK * WTBLK;
    for (size_t i = (size_t)blockIdx.x * blockDim.x + threadIdx.x; i < total;
         i += (size_t)gridDim.x * blockDim.x) {
        int e  = (int)(i & 7);
        int ln = (int)((i >> 3) & 63);
        size_t tile = i >> 9;
        int kg = (int)(tile % 36);
        size_t sb = tile / 36;
        int s   = (int)(sb & 3);
        int blk = (int)(sb >> 2);
        int jr  = blk * 16 + (ln & 15);
        int col = kg * 32 + (ln >> 4) * 8 + e;
        bf16 v = (bf16)0.f;
        if (jr < HIDD && col < HIDD)
            v = (bf16)ld_in(src, (size_t)(s * HIDD + jr) * HIDD + col, f32w);
        dst[i] = v;
    }
}

__global__ void combine_bias(const void* a, const void* b, float* o, int n, int np,
                             const int* __restrict__ dflag)
{
    const int f32w = *dflag;
    int i = blockIdx.x * blockDim.x + threadIdx.x;
    if (i < np) o[i] = (i < n) ? ld_in(a, i, f32w) + ld_in(b, i, f32w) : 0.f;
}

__global__ void cvt_bias(const void* a, float* o, int n, int np,
                         const int* __restrict__ dflag)
{
    const int f32w = *dflag;
    int i = blockIdx.x * blockDim.x + threadIdx.x;
    if (i < np) o[i] = (i < n) ? ld_in(a, i, f32w) : 0.f;
}

__global__ void embed_gather(const int* __restrict__ x, const void* __restrict__ emb,
                             bf16* __restrict__ XE, const int* __restrict__ dflag)
{
    const int f32w = *dflag;
    int row = blockIdx.x;                       // t*80+b
    int xi  = x[row];
    int b   = row % 80;
    bf16* base = XE + (size_t)(row / 80) * XSLAB;
    for (int c = threadIdx.x; c < KE; c += blockDim.x) {
        float v = (c < EMBD) ? ld_in(emb, (size_t)xi * EMBD + c, f32w) : 0.f;
        base[tflat(b, c, KC_E)] = (bf16)v;
    }
}

__global__ void zero_ha_pad(bf16* HA)
{
    int i = blockIdx.x * blockDim.x + threadIdx.x;
    if (i < MALL * 2) {
        int r = i >> 1;
        int t = r / BAT, b = r - t * BAT;
        int j = HIDD + (i & 1);
        HA[(size_t)t * HSLAB + tflat(b, j, KC_H)] = (bf16)0.f;
    }
}

__global__ void init_state(const void* __restrict__ h0, const void* __restrict__ c0,
                           size_t lofs, bf16* H0buf, float* Cst,
                           const int* __restrict__ dflag)
{
    const int f32w = *dflag;
    int i = blockIdx.x * blockDim.x + threadIdx.x;
    if (i >= BAT * KH) return;
    int b = i / KH, j = i % KH;
    float hv = 0.f, cv = 0.f;
    if (j < HIDD) {
        hv = ld_in(h0, lofs + (size_t)b * HIDD + j, f32w);
        cv = ld_in(c0, lofs + (size_t)b * HIDD + j, f32w);
    }
    H0buf[tflat(b, j, KC_H)] = (bf16)hv;
    Cst[i] = cv;
}

__global__ void write_tail(const bf16* __restrict__ Hfin, const float* __restrict__ Cfin,
                           void* __restrict__ outBase, size_t hOfs, size_t cOfs,
                           const int* __restrict__ dflag)
{
    const int f32w = *dflag;
    int i = blockIdx.x * blockDim.x + threadIdx.x;
    if (i >= BAT * HIDD) return;
    int b = i / HIDD, j = i % HIDD;
    float hv = clampdiag((float)Hfin[tflat(b, j, KC_H)]);
    float cv = clampdiag(Cfin[b * KH + j]);
    if (f32w) {
        ((float*)outBase)[hOfs + i] = hv;
        ((float*)outBase)[cOfs + i] = cv;
    } else {
        ((bf16*)outBase)[hOfs + i] = (bf16)hv;
        ((bf16*)outBase)[cOfs + i] = (bf16)cv;
    }
}

__global__ void sentinel_kernel(void* out, float v, const int* __restrict__ dflag)
{
    if (blockIdx.x == 0 && threadIdx.x == 0) {
        if (*dflag) ((float*)out)[0] = v;
        else        ((bf16*)out)[0] = (bf16)v;
    }
}

// ---------------------------------------------------------------------------
extern "C" void kernel_launch(void* const* d_in, const int* in_sizes, int n_in,
                              void* d_out, int out_size, void* d_ws, size_t ws_size,
                              hipStream_t stream)
{
    const int*  x    = (const int*)d_in[0];
    const void* h0   = d_in[1];
    const void* c0   = d_in[2];
    const void* emb  = d_in[3];
    const void* wih[3] = {d_in[4], d_in[8],  d_in[12]};
    const void* bih[3] = {d_in[5], d_in[9],  d_in[13]};
    const void* whh[3] = {d_in[6], d_in[10], d_in[14]};
    const void* bhh[3] = {d_in[7], d_in[11], d_in[15]};
    const void* wdec = d_in[16];
    const void* bdec = d_in[17];
    const size_t DEC = (size_t)MALL * NTOKV;
    (void)in_sizes; (void)n_in; (void)out_size;

    auto al = [](size_t v) { return (v + 255) & ~(size_t)255; };
    const size_t wdecB = al((size_t)NVP * KH * 2);
    auto plan = [&](bool gbf, size_t* offs) -> size_t {
        size_t off = 0;
        auto carve = [&](size_t b) { size_t p = off; off += al(b); return p; };
        offs[0] = carve((size_t)MALL * N4P * (gbf ? 2 : 4));     // G
        offs[1] = carve((size_t)MALL * KE * 2);                  // XE tiled
        offs[2] = carve((size_t)N4P * KH * 2);                   // WihP tiled
        offs[3] = carve((size_t)NBLK * WTBLK * 2);               // WT
        if (off < wdecB) off = wdecB;
        offs[4] = carve((size_t)MALL * KH * 2);                  // HA tiled
        offs[5] = carve((size_t)N4P * 4);                        // bc
        offs[6] = carve((size_t)NVP * 4);                        // bd
        offs[7] = carve((size_t)BAT * KH * 2);                   // H0 tiled
        offs[8] = carve((size_t)BAT * KH * 4);                   // Cst
        offs[9] = carve(256);                                    // dflag + barrier
        return off;
    };
    size_t offs[10];
    size_t needA = plan(false, offs);
    size_t needB = plan(true, offs);
    bool gbf16;
    if (ws_size >= needA)      { gbf16 = false; plan(false, offs); }
    else if (ws_size >= needB) { gbf16 = true;  plan(true,  offs); }
    else {
        int* dflag = (int*)d_ws;
        detect_dtype<<<1, 256, 0, stream>>>(emb, dflag);
        float mb = (float)(ws_size >> 20);
        if (mb > 20000.f) mb = 20000.f;
        sentinel_kernel<<<1, 64, 0, stream>>>(d_out, 700.f + mb, dflag);
        return;
    }

    char* ws = (char*)d_ws;
    void* G      = ws + offs[0];
    bf16* XE     = (bf16*)(ws + offs[1]);
    bf16* WihP   = (bf16*)(ws + offs[2]);
    bf16* WT     = (bf16*)(ws + offs[3]);
    bf16* WdecP  = (bf16*)(ws + 0);
    bf16* HA     = (bf16*)(ws + offs[4]);
    float* bc    = (float*)(ws + offs[5]);
    float* bd    = (float*)(ws + offs[6]);
    bf16* H0buf  = (bf16*)(ws + offs[7]);
    float* Cst   = (float*)(ws + offs[8]);
    int*  dflag  = (int*)(ws + offs[9]);
    int*  barctr = (int*)(ws + offs[9] + 128);

    detect_dtype<<<1, 256, 0, stream>>>(emb, dflag);
    embed_gather<<<MALL, 128, 0, stream>>>(x, emb, XE, dflag);
    zero_ha_pad<<<(MALL * 2 + 255) / 256, 256, 0, stream>>>(HA);

    for (int l = 0; l < 3; ++l) {
        int Kin = (l == 0) ? EMBD : HIDD;
        int kc  = (l == 0) ? KC_E : KC_H;
        int asl = (l == 0) ? XSLAB : HSLAB;
        pad_wtB<<<2048, 256, 0, stream>>>(wih[l], WihP, GATES, Kin, N4P / 16, kc, dflag);
        pad_wt<<<2048, 256, 0, stream>>>(whh[l], WT, dflag);
        combine_bias<<<(N4P + 255) / 256, 256, 0, stream>>>(bih[l], bhh[l], bc, GATES, N4P, dflag);
        init_state<<<(BAT * KH + 255) / 256, 256, 0, stream>>>(
            h0, c0, (size_t)l * BAT * HIDD, H0buf, Cst, dflag);
        bar_reset<<<1, 64, 0, stream>>>(barctr);
        const bf16* Ain = (l == 0) ? XE : HA;
        {
            int gx = N4P / 128, gy = (MALL + 127) / 128;
            gemm_bt<<<gx * gy, 256, 0, stream>>>(
                Ain, kc, asl, WihP, bc, G, N4P, MALL, N4P,
                gbf16 ? 1 : 0, dflag, gx, gy);
        }
        if (gbf16)
            lstm_layer<bf16><<<NBLK, 256, 0, stream>>>(
                WT, (const bf16*)G, H0buf, Cst, HA, barctr);
        else
            lstm_layer<float><<<NBLK, 256, 0, stream>>>(
                WT, (const float*)G, H0buf, Cst, HA, barctr);
        write_tail<<<(BAT * HIDD + 255) / 256, 256, 0, stream>>>(
            HA + (size_t)(SEQL - 1) * HSLAB, Cst, d_out,
            DEC + (size_t)l * BAT * HIDD,
            DEC + (size_t)3 * BAT * HIDD + (size_t)l * BAT * HIDD, dflag);
    }

    pad_wtB<<<4096, 256, 0, stream>>>(wdec, WdecP, NTOKV, HIDD, NVP / 16, KC_H, dflag);
    cvt_bias<<<(NVP + 255) / 256, 256, 0, stream>>>(bdec, bd, NTOKV, NVP, dflag);
    {
        int gx = NVP / 128, gy = (MALL + 127) / 128;
        gemm_bt<<<gx * gy, 256, 0, stream>>>(
            HA, KC_H, HSLAB, WdecP, bd, d_out, NTOKV, MALL, NTOKV, 2, dflag, gx, gy);
    }
}